// Round 16
// baseline (281.823 us; speedup 1.0000x reference)
//
#include <hip/hip_runtime.h>
#include <hip/hip_bf16.h>

typedef float f32x4 __attribute__((ext_vector_type(4)));
typedef float f32x16 __attribute__((ext_vector_type(16)));
typedef short s16x8 __attribute__((ext_vector_type(8)));
typedef unsigned short u16;
typedef unsigned short u16x8 __attribute__((ext_vector_type(8)));
typedef unsigned short u16x4 __attribute__((ext_vector_type(4)));
typedef unsigned int u32;
typedef unsigned int u32x4 __attribute__((ext_vector_type(4)));

#define MROWS 4096   // B*S
#define NQKV  3072   // NH*HD + 2*NKV*HD
#define DMODEL 2048

#define EXP2(x) __builtin_amdgcn_exp2f(x)

__device__ __forceinline__ u16 f2bf(float f) {
  __hip_bfloat16 h = __float2bfloat16(f);
  return __builtin_bit_cast(u16, h);
}
__device__ __forceinline__ float bf2f(u16 u) {
  __hip_bfloat16 h = __builtin_bit_cast(__hip_bfloat16, u);
  return __bfloat162float(h);
}

// HW packed f32->bf16 (RNE): dst.lo = bf16(a), dst.hi = bf16(b)
__device__ __forceinline__ u32 cvtpk(float a, float b) {
  u32 r;
  asm("v_cvt_pk_bf16_f32 %0, %1, %2" : "=v"(r) : "v"(a), "v"(b));
  return r;
}

typedef __attribute__((address_space(3))) unsigned int lds_u32_t;
typedef const __attribute__((address_space(1))) unsigned int glb_u32_t;
__device__ __forceinline__ void gload_lds16(const void* g, void* l) {
  __builtin_amdgcn_global_load_lds((glb_u32_t*)g, (lds_u32_t*)l, 16, 0, 0);
}

// ---------------- fp32 -> bf16 convert (x) ----------------
__global__ __launch_bounds__(256) void k_conv_x(const float* __restrict__ x, u16* __restrict__ o) {
  size_t i = ((size_t)blockIdx.x * 256 + threadIdx.x) * 4;
  float4 v = *(const float4*)(x + i);
  u16x4 r = { f2bf(v.x), f2bf(v.y), f2bf(v.z), f2bf(v.w) };
  *(u16x4*)(o + i) = r;
}

// ------- transpose + convert: src (K x N) f32 -> dst (N x K) bf16 -------
__global__ __launch_bounds__(256) void k_transw(const float* __restrict__ src, u16* __restrict__ dst,
                                                int N, int K) {
  __shared__ u16 t[64][68];
  int n0 = blockIdx.x * 64, k0 = blockIdx.y * 64;
  int tid = threadIdx.x;
#pragma unroll
  for (int r = 0; r < 4; ++r) {
    int k = r * 16 + (tid >> 4);
    int n = (tid & 15) * 4;
    float4 v = *(const float4*)(src + (size_t)(k0 + k) * N + n0 + n);
    t[n + 0][k] = f2bf(v.x);
    t[n + 1][k] = f2bf(v.y);
    t[n + 2][k] = f2bf(v.z);
    t[n + 3][k] = f2bf(v.w);
  }
  __syncthreads();
#pragma unroll
  for (int r = 0; r < 4; ++r) {
    int n = r * 16 + (tid >> 4);
    int k = (tid & 15) * 4;
    u16x4 o = { t[n][k], t[n][k + 1], t[n][k + 2], t[n][k + 3] };
    *(u16x4*)(dst + (size_t)(n0 + n) * K + k0 + k) = o;
  }
}

// ------ bf16 GEMM v4: 2-phase-per-K-tile counted-vmcnt pipeline ------
template <int BM, int BN, typename OutT>
__global__ __launch_bounds__(512, 2)
void k_gemm8(const u16* __restrict__ A, const u16* __restrict__ Bt,
             OutT* __restrict__ C, int M, int N, int K, int nbx) {
  static_assert(BM == 128, "A staging assumes one full 512x16B round");
  constexpr int WM = 2, WN = 4;
  constexpr int MF = BM / 16 / WM;   // 4
  constexpr int NF = BN / 16 / WN;   // 2 (BN=128), 3 (BN=192), 4 (BN=256)
  __shared__ u16 sA[2][2][BM][32];
  __shared__ u16 sB[2][2][BN][32];
  const int nwg = gridDim.x;
  const int chunk = nwg >> 3;
  const int wg = (blockIdx.x & 7) * chunk + (blockIdx.x >> 3);
  const int m0 = (wg / nbx) * BM, n0 = (wg % nbx) * BN;
  const int tid = threadIdx.x;
  const int l = tid & 63;
  const int lo = l & 15, hi = l >> 4;
  const int wid = tid >> 6;
  const int wm = wid >> 2, wn = wid & 3;
  const int nkt = K >> 6;  // 64-wide K tiles

  f32x4 acc[MF][NF] = {};

  auto STAGE = [&](int buf, int ks, int t) {
    {  // A chunk: BM*64B = 8KB = exactly one round
      const int D = tid * 16;
      const int row = D >> 6;
      const int srcb = (D & 63) ^ (((row >> 1) & 3) << 4);
      gload_lds16((const char*)(A + (size_t)(m0 + row) * K + t * 64 + ks * 32) + srcb,
                  (char*)(&sA[buf][ks][0][0]) + D);
    }
#pragma unroll
    for (int i = 0; i < 2; ++i) {  // B chunk: BN*64B
      const int u = i * 512 + tid;
      if (u < BN * 4) {
        const int D = u * 16;
        const int row = D >> 6;
        const int srcb = (D & 63) ^ (((row >> 1) & 3) << 4);
        gload_lds16((const char*)(Bt + (size_t)(n0 + row) * K + t * 64 + ks * 32) + srcb,
                    (char*)(&sB[buf][ks][0][0]) + D);
      }
    }
  };

  auto WAITVM = [&]() {  // leave exactly one phase's own issues in flight
    if constexpr (BN == 192) {
      if (wid < 4) asm volatile("s_waitcnt vmcnt(3)" ::: "memory");
      else         asm volatile("s_waitcnt vmcnt(2)" ::: "memory");
    } else if constexpr (BN == 256) {
      asm volatile("s_waitcnt vmcnt(3)" ::: "memory");
    } else {  // BN == 128: 2 issues per phase per thread
      asm volatile("s_waitcnt vmcnt(2)" ::: "memory");
    }
  };

  auto PHASE = [&](int buf, int ks, int t1, bool st, int vmmode) {
    s16x8 a[MF], b[NF];
#pragma unroll
    for (int mf = 0; mf < MF; ++mf) {
      const int row = wm * (MF * 16) + mf * 16 + lo;
      a[mf] = *(const s16x8*)((const char*)(&sA[buf][ks][0][0]) + row * 64 +
                              ((hi * 16) ^ (((row >> 1) & 3) << 4)));
    }
#pragma unroll
    for (int nf = 0; nf < NF; ++nf) {
      const int row = wn * (NF * 16) + nf * 16 + lo;
      b[nf] = *(const s16x8*)((const char*)(&sB[buf][ks][0][0]) + row * 64 +
                              ((hi * 16) ^ (((row >> 1) & 3) << 4)));
    }
    if (st) STAGE(buf ^ 1, ks, t1);
    __builtin_amdgcn_sched_barrier(0);
    __builtin_amdgcn_s_barrier();
    asm volatile("s_waitcnt lgkmcnt(0)" ::: "memory");
    __builtin_amdgcn_sched_barrier(0);
    __builtin_amdgcn_s_setprio(1);
#pragma unroll
    for (int mf = 0; mf < MF; ++mf)
#pragma unroll
      for (int nf = 0; nf < NF; ++nf)
        acc[mf][nf] = __builtin_amdgcn_mfma_f32_16x16x32_bf16(a[mf], b[nf], acc[mf][nf], 0, 0, 0);
    __builtin_amdgcn_s_setprio(0);
    if (vmmode == 1) WAITVM();
    else if (vmmode == 2) asm volatile("s_waitcnt vmcnt(0)" ::: "memory");
    __builtin_amdgcn_sched_barrier(0);
    __builtin_amdgcn_s_barrier();
  };

  STAGE(0, 0, 0);
  STAGE(0, 1, 0);
  WAITVM();
  __builtin_amdgcn_s_barrier();

  for (int t = 0; t < nkt; ++t) {
    const int buf = t & 1;
    const bool st = (t + 1 < nkt);
    PHASE(buf, 0, t + 1, st, st ? 1 : 2);
    PHASE(buf, 1, t + 1, st, st ? 1 : 0);
  }

#pragma unroll
  for (int mf = 0; mf < MF; ++mf)
#pragma unroll
    for (int nf = 0; nf < NF; ++nf)
#pragma unroll
      for (int r = 0; r < 4; ++r) {
        const int row = m0 + wm * (MF * 16) + mf * 16 + hi * 4 + r;
        const int col = n0 + wn * (NF * 16) + nf * 16 + lo;
        if constexpr (__is_same(OutT, float)) C[(size_t)row * N + col] = acc[mf][nf][r];
        else                                  C[(size_t)row * N + col] = f2bf(acc[mf][nf][r]);
      }
}

// ------- fused RMSNorm + RoPE; one wave per (row, head) vector -------
__global__ __launch_bounds__(256) void k_normrope(const u16* __restrict__ qkv, u16* __restrict__ qn,
                                                  u16* __restrict__ kn, const float* __restrict__ qs,
                                                  const float* __restrict__ ksc,
                                                  const float* __restrict__ cosb,
                                                  const float* __restrict__ sinb) {
  int j = blockIdx.x * 4 + (threadIdx.x >> 6);
  int l = threadIdx.x & 63;
  bool isQ = j < MROWS * 32;
  int m, head, incol;
  if (isQ) { m = j >> 5; head = j & 31; incol = head * 64; }
  else     { int j2 = j - MROWS * 32; m = j2 >> 3; head = j2 & 7; incol = 2048 + head * 64; }
  float v = bf2f(qkv[(size_t)m * NQKV + incol + l]);
  float ss = v * v;
#pragma unroll
  for (int off = 1; off < 64; off <<= 1) ss += __shfl_xor(ss, off, 64);
  float inv = rsqrtf(ss * (1.0f / 64.0f) + 1e-6f);
  float nx = v * inv * (isQ ? qs[l] : ksc[l]);
  int s = m & 2047;
  float c = cosb[s * 64 + l], sn = sinb[s * 64 + l];
  float partner = __shfl_xor(nx, 32, 64);
  float rot = (l < 32) ? -partner : partner;
  float outv = nx * c + rot * sn;
  if (isQ) {
    outv *= 0.125f * 1.44269504088896f;  // fold 1/sqrt(HD) and log2(e) into Q
    qn[(size_t)m * 2048 + incol + l] = f2bf(outv);
  } else {
    kn[(size_t)m * 512 + head * 64 + l] = f2bf(outv);
  }
}

// ------- V transpose: QKV v-region -> vt[(b*8+kv)*64 + d][s] -------
__global__ __launch_bounds__(256) void k_vtrans(const u16* __restrict__ qkv, u16* __restrict__ vt) {
  __shared__ u16 t[64][68];
  int s0 = blockIdx.x * 64;
  int bk = blockIdx.y;  // b*8 + kv
  int tid = threadIdx.x;
#pragma unroll
  for (int r = 0; r < 4; ++r) {
    int s = r * 16 + (tid >> 4);
    int d = (tid & 15) * 4;
    u16x4 v = *(const u16x4*)(qkv + (size_t)((bk >> 3) * 2048 + s0 + s) * NQKV + 2560 + (bk & 7) * 64 + d);
    t[d + 0][s] = v[0];
    t[d + 1][s] = v[1];
    t[d + 2][s] = v[2];
    t[d + 3][s] = v[3];
  }
  __syncthreads();
#pragma unroll
  for (int r = 0; r < 4; ++r) {
    int d = r * 16 + (tid >> 4);
    int sl = (tid & 15) * 4;
    u16x4 o = { t[d][sl], t[d][sl + 1], t[d][sl + 2], t[d][sl + 3] };
    *(u16x4*)(vt + (size_t)(bk * 64 + d) * 2048 + s0 + sl) = o;
  }
}

// ------- causal flash attention v9: LDS-FREE K/V (direct L2/L1 frag loads).
// K/V cache-fit per XCD (2MB vs 4MB L2) -> staging was pure overhead
// (3x byte movement + barriers + bank conflicts). sigma moves into the K
// ADDRESS (sigma^-1(l31) precomputed) so register contents — and therefore
// the causal mask and the zero-shuffle PV — are identical to v8b.
// No barriers in the superstep loop; LDS only for the per-q-tile merge.
__global__ __launch_bounds__(512, 2) void k_attn(const u16* __restrict__ qn, const u16* __restrict__ kn,
                                                 const u16* __restrict__ vt, u16* __restrict__ aout) {
  __shared__ float mOL[128 * 65 + 128];  // merge buffer only (~33.8KB)
  float* mO = mOL;
  float* mL = mOL + 128 * 65;
  const int bid = blockIdx.x;           // 512 blocks
  const int kvh = bid & 7;              // XCD-locality
  const int b = (bid >> 3) & 1;
  const int hsub = (bid >> 4) & 3;
  const int p = bid >> 6;               // 0..7
  const int h = kvh * 4 + hsub;
  const int tid = threadIdx.x, l = tid & 63;
  const int w = tid >> 6, qw = w & 3, half = w >> 2;
  const int l31 = l & 31, l5 = l >> 5;
  const int qtA = 15 - p, qtB = p;
  const u16* kbase = kn + (size_t)(b * 2048) * 512 + kvh * 64;
  const u16* vbase = vt + (size_t)((b * 8 + kvh) * 64) * 2048;
  // sigma^-1(l31): global K row whose data must land in frag row l31
  const int B_ = (l31 >> 3) & 3, h_ = (l31 >> 2) & 1, c_ = l31 & 3;
  const int sigi = 16 * (B_ >> 1) + 8 * h_ + 4 * (B_ & 1) + c_;

  s16x8 qf[4];
  f32x16 O0, O1;
  float lst;

  for (int mem = 0; mem < 2; ++mem) {
    const int qt = mem ? qtB : qtA;
    const int row = qw * 32 + l31;  // block-local q row
    {
      const u16* qp = qn + (size_t)(b * 2048 + qt * 128 + row) * 2048 + h * 64 + l5 * 8;
#pragma unroll
      for (int ki = 0; ki < 4; ++ki) qf[ki] = *(const s16x8*)(qp + ki * 16);
#pragma unroll
      for (int r = 0; r < 16; ++r) { O0[r] = 0.f; O1[r] = 0.f; }
      lst = 0.f;
    }
    const int nss = qt + 1;
    for (int i = 0; i < nss; ++i) {
      const int T = 2 * i + half;  // my KV tile
      const int kv0 = T * 64;
      // ---- QK^T: K frags straight from global (sigma^-1 row addressing)
      f32x16 sc0, sc1;
#pragma unroll
      for (int r = 0; r < 16; ++r) { sc0[r] = 0.f; sc1[r] = 0.f; }
      __builtin_amdgcn_s_setprio(1);
#pragma unroll
      for (int ki = 0; ki < 4; ++ki) {
        const u16* kp = kbase + (size_t)(kv0 + sigi) * 512 + ki * 16 + l5 * 8;
        s16x8 a0 = *(const s16x8*)kp;
        s16x8 a1 = *(const s16x8*)(kp + (size_t)32 * 512);
        sc0 = __builtin_amdgcn_mfma_f32_32x32x16_bf16(a0, qf[ki], sc0, 0, 0, 0);
        sc1 = __builtin_amdgcn_mfma_f32_32x32x16_bf16(a1, qf[ki], sc1, 0, 0, 0);
      }
      __builtin_amdgcn_s_setprio(0);
      // ---- causal mask (sigma-inverse key index); last superstep only
      if (T >= 2 * qt) {
        const int qrow = qt * 128 + row;
        const int kb0 = T * 64 + 8 * l5;
#pragma unroll
        for (int r = 0; r < 16; ++r) {
          const int klocal = 16 * (r >> 3) + 4 * ((r >> 2) & 1) + (r & 3);
          if (kb0 + klocal > qrow) sc0[r] = -1e30f;
          if (kb0 + 32 + klocal > qrow) sc1[r] = -1e30f;
        }
      }
      // ---- fixed-scale softmax: P = exp2(score)
      float rs = 0.f;
      u32 pk0[4][2], pk1[4][2];
#pragma unroll
      for (int g = 0; g < 4; ++g) {
        float a0 = EXP2(sc0[4*g+0]), a1 = EXP2(sc0[4*g+1]);
        float a2 = EXP2(sc0[4*g+2]), a3 = EXP2(sc0[4*g+3]);
        float b0 = EXP2(sc1[4*g+0]), b1 = EXP2(sc1[4*g+1]);
        float b2 = EXP2(sc1[4*g+2]), b3 = EXP2(sc1[4*g+3]);
        rs += ((a0 + a1) + (a2 + a3)) + ((b0 + b1) + (b2 + b3));
        pk0[g][0] = cvtpk(a0, a1);
        pk0[g][1] = cvtpk(a2, a3);
        pk1[g][0] = cvtpk(b0, b1);
        pk1[g][1] = cvtpk(b2, b3);
      }
      rs += __shfl_xor(rs, 32, 64);
      lst += rs;
      // ---- PV: P already in B-frag layout; V frags straight from global
#define PV_STEP(PK, GB, KB)                                                   \
      {                                                                       \
        u32x4 wv_ = { PK[GB][0], PK[GB][1], PK[GB+1][0], PK[GB+1][1] };       \
        s16x8 pb = __builtin_bit_cast(s16x8, wv_);                            \
        const u16* vp = vbase + (size_t)l31 * 2048 + kv0 + (KB) * 16 + l5 * 8; \
        s16x8 v0 = *(const s16x8*)vp;                                         \
        s16x8 v1 = *(const s16x8*)(vp + (size_t)32 * 2048);                   \
        __builtin_amdgcn_s_setprio(1);                                        \
        O0 = __builtin_amdgcn_mfma_f32_32x32x16_bf16(v0, pb, O0, 0, 0, 0);    \
        O1 = __builtin_amdgcn_mfma_f32_32x32x16_bf16(v1, pb, O1, 0, 0, 0);    \
        __builtin_amdgcn_s_setprio(0);                                        \
      }
      PV_STEP(pk0, 0, 0)
      PV_STEP(pk0, 2, 1)
      PV_STEP(pk1, 0, 2)
      PV_STEP(pk1, 2, 3)
#undef PV_STEP
    }
    // ---- merge the two halves' partial (O, lst), then store
    __syncthreads();  // all waves done with previous merge-buffer use
    if (half == 1) {
#pragma unroll
      for (int g = 0; g < 4; ++g)
#pragma unroll
        for (int j = 0; j < 4; ++j) {
          const int d = 8 * g + 4 * l5 + j;
          mO[row * 65 + d] = O0[4*g+j];
          mO[row * 65 + 32 + d] = O1[4*g+j];
        }
      if (l5 == 0) mL[row] = lst;
    }
    __syncthreads();
    if (half == 0) {
      const float inv = 1.0f / (lst + mL[row]);
      const size_t rowoff = (size_t)(b * 2048 + qt * 128 + row) * 2048 + h * 64;
#pragma unroll
      for (int g = 0; g < 4; ++g) {
        const int d0 = 8 * g + 4 * l5;
        u16x4 o0 = { f2bf((O0[4*g+0] + mO[row*65+d0+0]) * inv),
                     f2bf((O0[4*g+1] + mO[row*65+d0+1]) * inv),
                     f2bf((O0[4*g+2] + mO[row*65+d0+2]) * inv),
                     f2bf((O0[4*g+3] + mO[row*65+d0+3]) * inv) };
        *(u16x4*)(aout + rowoff + d0) = o0;
        u16x4 o1 = { f2bf((O1[4*g+0] + mO[row*65+32+d0+0]) * inv),
                     f2bf((O1[4*g+1] + mO[row*65+32+d0+1]) * inv),
                     f2bf((O1[4*g+2] + mO[row*65+32+d0+2]) * inv),
                     f2bf((O1[4*g+3] + mO[row*65+32+d0+3]) * inv) };
        *(u16x4*)(aout + rowoff + 32 + d0) = o1;
      }
    }
    __syncthreads();  // merge reads done before next member's writes
  }
}

extern "C" void kernel_launch(void* const* d_in, const int* in_sizes, int n_in,
                              void* d_out, int out_size, void* d_ws, size_t ws_size,
                              hipStream_t stream) {
  (void)in_sizes; (void)n_in; (void)out_size; (void)ws_size;
  const float* x    = (const float*)d_in[0];
  const float* wq   = (const float*)d_in[1];
  const float* wk   = (const float*)d_in[2];
  const float* wv   = (const float*)d_in[3];
  const float* wo   = (const float*)d_in[4];
  const float* qs   = (const float*)d_in[5];
  const float* ksc  = (const float*)d_in[6];
  const float* cosb = (const float*)d_in[7];
  const float* sinb = (const float*)d_in[8];
  float* out = (float*)d_out;
  char* ws = (char*)d_ws;
  u16* xbf   = (u16*)(ws);                 // 16 MB  4096x2048 bf16
  u16* wqkvt = (u16*)(ws + 16777216);      // 12 MB  3072x2048 bf16 (W^T)
  u16* wot   = (u16*)(ws + 29360128);      // 8 MB   2048x2048 bf16 (Wo^T)
  u16* qkv   = (u16*)(ws + 37748736);      // 24 MB  4096x3072 bf16
  u16* qn    = (u16*)(ws + 62914560);      // 16 MB  4096x2048 bf16
  u16* kn    = (u16*)(ws + 79691776);      // 4 MB   4096x512 bf16
  u16* vt    = (u16*)(ws + 83886080);      // 4 MB   (b,kv,d) x 2048 bf16
  u16* aout  = (u16*)(ws + 88080384);      // 16 MB  4096x2048 bf16

  k_conv_x<<<8192, 256, 0, stream>>>(x, xbf);
  k_transw<<<dim3(32, 32), 256, 0, stream>>>(wq, wqkvt, 2048, 2048);
  k_transw<<<dim3(8, 32), 256, 0, stream>>>(wk, wqkvt + (size_t)2048 * 2048, 512, 2048);
  k_transw<<<dim3(8, 32), 256, 0, stream>>>(wv, wqkvt + (size_t)2560 * 2048, 512, 2048);
  k_transw<<<dim3(32, 32), 256, 0, stream>>>(wo, wot, 2048, 2048);
  // QKV: 128x192 tiles -> 32x16 = 512 blocks, 2 blocks/CU (80KB LDS), exact fill
  k_gemm8<128, 192, u16><<<512, 512, 0, stream>>>(xbf, wqkvt, qkv, MROWS, NQKV, 2048, 16);
  k_normrope<<<40960, 256, 0, stream>>>(qkv, qn, kn, qs, ksc, cosb, sinb);
  k_vtrans<<<dim3(32, 16), 256, 0, stream>>>(qkv, vt);
  k_attn<<<512, 512, 0, stream>>>(qn, kn, vt, aout);
  // OUT: 128x128 tiles -> 32x16 = 512 blocks, 2 blocks/CU (64KB LDS), exact fill
  k_gemm8<128, 128, float><<<512, 512, 0, stream>>>(aout, wot, out, MROWS, DMODEL, 2048, 16);
}

// Round 17
// 207.788 us; speedup vs baseline: 1.3563x; 1.3563x over previous
//
#include <hip/hip_runtime.h>
#include <hip/hip_bf16.h>

typedef float f32x4 __attribute__((ext_vector_type(4)));
typedef float f32x16 __attribute__((ext_vector_type(16)));
typedef short s16x8 __attribute__((ext_vector_type(8)));
typedef unsigned short u16;
typedef unsigned short u16x8 __attribute__((ext_vector_type(8)));
typedef unsigned short u16x4 __attribute__((ext_vector_type(4)));
typedef unsigned int u32;
typedef unsigned int u32x4 __attribute__((ext_vector_type(4)));

#define MROWS 4096   // B*S
#define NQKV  3072   // NH*HD + 2*NKV*HD
#define DMODEL 2048

#define EXP2(x) __builtin_amdgcn_exp2f(x)

__device__ __forceinline__ u16 f2bf(float f) {
  __hip_bfloat16 h = __float2bfloat16(f);
  return __builtin_bit_cast(u16, h);
}
__device__ __forceinline__ float bf2f(u16 u) {
  __hip_bfloat16 h = __builtin_bit_cast(__hip_bfloat16, u);
  return __bfloat162float(h);
}

// HW packed f32->bf16 (RNE): dst.lo = bf16(a), dst.hi = bf16(b)
__device__ __forceinline__ u32 cvtpk(float a, float b) {
  u32 r;
  asm("v_cvt_pk_bf16_f32 %0, %1, %2" : "=v"(r) : "v"(a), "v"(b));
  return r;
}

typedef __attribute__((address_space(3))) unsigned int lds_u32_t;
typedef const __attribute__((address_space(1))) unsigned int glb_u32_t;
__device__ __forceinline__ void gload_lds16(const void* g, void* l) {
  __builtin_amdgcn_global_load_lds((glb_u32_t*)g, (lds_u32_t*)l, 16, 0, 0);
}

// ---------------- fp32 -> bf16 convert (x) ----------------
__global__ __launch_bounds__(256) void k_conv_x(const float* __restrict__ x, u16* __restrict__ o) {
  size_t i = ((size_t)blockIdx.x * 256 + threadIdx.x) * 4;
  float4 v = *(const float4*)(x + i);
  u16x4 r = { f2bf(v.x), f2bf(v.y), f2bf(v.z), f2bf(v.w) };
  *(u16x4*)(o + i) = r;
}

// ------- transpose + convert: src (K x N) f32 -> dst (N x K) bf16 -------
__global__ __launch_bounds__(256) void k_transw(const float* __restrict__ src, u16* __restrict__ dst,
                                                int N, int K) {
  __shared__ u16 t[64][68];
  int n0 = blockIdx.x * 64, k0 = blockIdx.y * 64;
  int tid = threadIdx.x;
#pragma unroll
  for (int r = 0; r < 4; ++r) {
    int k = r * 16 + (tid >> 4);
    int n = (tid & 15) * 4;
    float4 v = *(const float4*)(src + (size_t)(k0 + k) * N + n0 + n);
    t[n + 0][k] = f2bf(v.x);
    t[n + 1][k] = f2bf(v.y);
    t[n + 2][k] = f2bf(v.z);
    t[n + 3][k] = f2bf(v.w);
  }
  __syncthreads();
#pragma unroll
  for (int r = 0; r < 4; ++r) {
    int n = r * 16 + (tid >> 4);
    int k = (tid & 15) * 4;
    u16x4 o = { t[n][k], t[n][k + 1], t[n][k + 2], t[n][k + 3] };
    *(u16x4*)(dst + (size_t)(n0 + n) * K + k0 + k) = o;
  }
}

// ------ bf16 GEMM v5: 2-phase skeleton with 3-CHUNK-AHEAD staging.
// Chunk c (=2t+ks) is staged at phase c-3 into slot (c&3)=[tile&1][ks];
// WAITVM leaves 2 phases' issues in flight (counted), giving each chunk
// ~3 phases (~1200cyc) to cover HBM latency. Slot reuse distance = 4
// phases; WAR safe: slot's reads drained at its phase's lgkmcnt(0)+barrier.
template <int BM, int BN, typename OutT>
__global__ __launch_bounds__(512, 2)
void k_gemm8(const u16* __restrict__ A, const u16* __restrict__ Bt,
             OutT* __restrict__ C, int M, int N, int K, int nbx) {
  static_assert(BM == 128, "A staging assumes one full 512x16B round");
  constexpr int WM = 2, WN = 4;
  constexpr int MF = BM / 16 / WM;   // 4
  constexpr int NF = BN / 16 / WN;   // 2 (BN=128), 3 (BN=192), 4 (BN=256)
  __shared__ u16 sA[2][2][BM][32];
  __shared__ u16 sB[2][2][BN][32];
  const int nwg = gridDim.x;
  const int chunk = nwg >> 3;
  const int wg = (blockIdx.x & 7) * chunk + (blockIdx.x >> 3);
  const int m0 = (wg / nbx) * BM, n0 = (wg % nbx) * BN;
  const int tid = threadIdx.x;
  const int l = tid & 63;
  const int lo = l & 15, hi = l >> 4;
  const int wid = tid >> 6;
  const int wm = wid >> 2, wn = wid & 3;
  const int nkt = K >> 6;  // 64-wide K tiles

  f32x4 acc[MF][NF] = {};

  // stage tile t's chunk ks into slot [t&1][ks]
  auto STAGE = [&](int ks, int t) {
    const int buf = t & 1;
    {  // A chunk: BM*64B = 8KB = exactly one round
      const int D = tid * 16;
      const int row = D >> 6;
      const int srcb = (D & 63) ^ (((row >> 1) & 3) << 4);
      gload_lds16((const char*)(A + (size_t)(m0 + row) * K + t * 64 + ks * 32) + srcb,
                  (char*)(&sA[buf][ks][0][0]) + D);
    }
#pragma unroll
    for (int i = 0; i < 2; ++i) {  // B chunk: BN*64B
      const int u = i * 512 + tid;
      if (u < BN * 4) {
        const int D = u * 16;
        const int row = D >> 6;
        const int srcb = (D & 63) ^ (((row >> 1) & 3) << 4);
        gload_lds16((const char*)(Bt + (size_t)(n0 + row) * K + t * 64 + ks * 32) + srcb,
                    (char*)(&sB[buf][ks][0][0]) + D);
      }
    }
  };

  auto WAITVM = [&]() {  // leave exactly TWO phases' own issues in flight
    if constexpr (BN == 192) {
      if (wid < 4) asm volatile("s_waitcnt vmcnt(6)" ::: "memory");
      else         asm volatile("s_waitcnt vmcnt(4)" ::: "memory");
    } else if constexpr (BN == 256) {
      asm volatile("s_waitcnt vmcnt(6)" ::: "memory");
    } else {  // BN == 128: 2 issues per phase per wave
      asm volatile("s_waitcnt vmcnt(4)" ::: "memory");
    }
  };

  auto PHASE = [&](int buf, int ks, bool st, int st_ks, int st_t) {
    s16x8 a[MF], b[NF];
#pragma unroll
    for (int mf = 0; mf < MF; ++mf) {
      const int row = wm * (MF * 16) + mf * 16 + lo;
      a[mf] = *(const s16x8*)((const char*)(&sA[buf][ks][0][0]) + row * 64 +
                              ((hi * 16) ^ (((row >> 1) & 3) << 4)));
    }
#pragma unroll
    for (int nf = 0; nf < NF; ++nf) {
      const int row = wn * (NF * 16) + nf * 16 + lo;
      b[nf] = *(const s16x8*)((const char*)(&sB[buf][ks][0][0]) + row * 64 +
                              ((hi * 16) ^ (((row >> 1) & 3) << 4)));
    }
    if (st) STAGE(st_ks, st_t);
    __builtin_amdgcn_sched_barrier(0);
    __builtin_amdgcn_s_barrier();
    asm volatile("s_waitcnt lgkmcnt(0)" ::: "memory");
    __builtin_amdgcn_sched_barrier(0);
    __builtin_amdgcn_s_setprio(1);
#pragma unroll
    for (int mf = 0; mf < MF; ++mf)
#pragma unroll
      for (int nf = 0; nf < NF; ++nf)
        acc[mf][nf] = __builtin_amdgcn_mfma_f32_16x16x32_bf16(a[mf], b[nf], acc[mf][nf], 0, 0, 0);
    __builtin_amdgcn_s_setprio(0);
    if (st) WAITVM();
    else    asm volatile("s_waitcnt vmcnt(0)" ::: "memory");
    __builtin_amdgcn_sched_barrier(0);
    __builtin_amdgcn_s_barrier();
  };

  // prologue: stage chunks 0,1,2 = (0,0),(0,1),(1,0)
  STAGE(0, 0);
  STAGE(1, 0);
  STAGE(0, 1);
  WAITVM();               // drains chunk (0,0); leaves (0,1),(1,0) in flight
  __builtin_amdgcn_s_barrier();

  for (int t = 0; t < nkt; ++t) {
    const int buf = t & 1;
    // phase (t,0): stage chunk (t+1, ks=1); phase (t,1): stage (t+2, ks=0)
    PHASE(buf, 0, t + 1 < nkt, 1, t + 1);
    PHASE(buf, 1, t + 2 < nkt, 0, t + 2);
  }

#pragma unroll
  for (int mf = 0; mf < MF; ++mf)
#pragma unroll
    for (int nf = 0; nf < NF; ++nf)
#pragma unroll
      for (int r = 0; r < 4; ++r) {
        const int row = m0 + wm * (MF * 16) + mf * 16 + hi * 4 + r;
        const int col = n0 + wn * (NF * 16) + nf * 16 + lo;
        if constexpr (__is_same(OutT, float)) C[(size_t)row * N + col] = acc[mf][nf][r];
        else                                  C[(size_t)row * N + col] = f2bf(acc[mf][nf][r]);
      }
}

// ------- fused RMSNorm + RoPE; one wave per (row, head) vector -------
__global__ __launch_bounds__(256) void k_normrope(const u16* __restrict__ qkv, u16* __restrict__ qn,
                                                  u16* __restrict__ kn, const float* __restrict__ qs,
                                                  const float* __restrict__ ksc,
                                                  const float* __restrict__ cosb,
                                                  const float* __restrict__ sinb) {
  int j = blockIdx.x * 4 + (threadIdx.x >> 6);
  int l = threadIdx.x & 63;
  bool isQ = j < MROWS * 32;
  int m, head, incol;
  if (isQ) { m = j >> 5; head = j & 31; incol = head * 64; }
  else     { int j2 = j - MROWS * 32; m = j2 >> 3; head = j2 & 7; incol = 2048 + head * 64; }
  float v = bf2f(qkv[(size_t)m * NQKV + incol + l]);
  float ss = v * v;
#pragma unroll
  for (int off = 1; off < 64; off <<= 1) ss += __shfl_xor(ss, off, 64);
  float inv = rsqrtf(ss * (1.0f / 64.0f) + 1e-6f);
  float nx = v * inv * (isQ ? qs[l] : ksc[l]);
  int s = m & 2047;
  float c = cosb[s * 64 + l], sn = sinb[s * 64 + l];
  float partner = __shfl_xor(nx, 32, 64);
  float rot = (l < 32) ? -partner : partner;
  float outv = nx * c + rot * sn;
  if (isQ) {
    outv *= 0.125f * 1.44269504088896f;  // fold 1/sqrt(HD) and log2(e) into Q
    qn[(size_t)m * 2048 + incol + l] = f2bf(outv);
  } else {
    kn[(size_t)m * 512 + head * 64 + l] = f2bf(outv);
  }
}

// ------- V transpose: QKV v-region -> vt[(b*8+kv)*64 + d][s] -------
__global__ __launch_bounds__(256) void k_vtrans(const u16* __restrict__ qkv, u16* __restrict__ vt) {
  __shared__ u16 t[64][68];
  int s0 = blockIdx.x * 64;
  int bk = blockIdx.y;  // b*8 + kv
  int tid = threadIdx.x;
#pragma unroll
  for (int r = 0; r < 4; ++r) {
    int s = r * 16 + (tid >> 4);
    int d = (tid & 15) * 4;
    u16x4 v = *(const u16x4*)(qkv + (size_t)((bk >> 3) * 2048 + s0 + s) * NQKV + 2560 + (bk & 7) * 64 + d);
    t[d + 0][s] = v[0];
    t[d + 1][s] = v[1];
    t[d + 2][s] = v[2];
    t[d + 3][s] = v[3];
  }
  __syncthreads();
#pragma unroll
  for (int r = 0; r < 4; ++r) {
    int d = r * 16 + (tid >> 4);
    int sl = (tid & 15) * 4;
    u16x4 o = { t[d][sl], t[d][sl + 1], t[d][sl + 2], t[d][sl + 3] };
    *(u16x4*)(vt + (size_t)(bk * 64 + d) * 2048 + s0 + sl) = o;
  }
}

// ------- causal flash attention v8b (round-15 proven version, restored) -------
__global__ __launch_bounds__(512, 2) void k_attn(const u16* __restrict__ qn, const u16* __restrict__ kn,
                                                 const u16* __restrict__ vt, u16* __restrict__ aout) {
  __shared__ char sKV[4][2][64 * 128];  // [buf][K|V][row][128B], 64KB
  float* mO = (float*)&sKV[0][0][0];    // merge buffer alias: 128 x 65 f32
  float* mL = mO + 128 * 65;            // + 128 f32 lst
  const int bid = blockIdx.x;           // 512 blocks
  const int kvh = bid & 7;              // XCD-locality
  const int b = (bid >> 3) & 1;
  const int hsub = (bid >> 4) & 3;
  const int p = bid >> 6;               // 0..7
  const int h = kvh * 4 + hsub;
  const int tid = threadIdx.x, l = tid & 63;
  const int w = tid >> 6, qw = w & 3, half = w >> 2;
  const int l31 = l & 31, l5 = l >> 5;
  const int qtA = 15 - p, qtB = p;
  const u16* kbase = kn + (size_t)(b * 2048) * 512 + kvh * 64;
  const u16* vbase = vt + (size_t)((b * 8 + kvh) * 64) * 2048;
  const int st = tid >> 8;
  const int stid = tid & 255;
  const int srow = stid >> 3;
  const int scol = (stid & 7) * 8;
  const int sg_t = srow >> 4, sg_h = (srow >> 3) & 1, sg_j = srow & 7;
  const int krow0 = 32 * (sg_t >> 1) + 8 * ((sg_t & 1) * 2 + (sg_j >> 2)) + 4 * sg_h + (sg_j & 3);

  u16x8 krg0, krg1, vrg0, vrg1;
  int stbuf = 0;
  auto issue = [&](int baset) {
    const int tile = baset + st;
    const int kv0 = tile * 64;
    stbuf = tile & 3;
    krg0 = *(const u16x8*)(kbase + (size_t)(kv0 + srow) * 512 + scol);
    krg1 = *(const u16x8*)(kbase + (size_t)(kv0 + srow + 32) * 512 + scol);
    vrg0 = *(const u16x8*)(vbase + (size_t)srow * 2048 + kv0 + scol);
    vrg1 = *(const u16x8*)(vbase + (size_t)(srow + 32) * 2048 + kv0 + scol);
  };
  auto stash = [&]() {
    char* sK = sKV[stbuf][0];
    char* sV = sKV[stbuf][1];
    const int cb = scol * 2;
    const int k0_ = krow0, k1_ = krow0 + 32;
    *(u16x8*)(sK + k0_ * 128 + (cb ^ ((k0_ & 7) << 4))) = krg0;
    *(u16x8*)(sK + k1_ * 128 + (cb ^ ((k1_ & 7) << 4))) = krg1;
    const int r0 = srow, r1 = srow + 32;
    *(u16x8*)(sV + r0 * 128 + (cb ^ ((r0 & 7) << 4))) = vrg0;
    *(u16x8*)(sV + r1 * 128 + (cb ^ ((r1 & 7) << 4))) = vrg1;
  };

  s16x8 qf[4];
  f32x16 O0, O1;
  float lst;

  for (int mem = 0; mem < 2; ++mem) {
    const int qt = mem ? qtB : qtA;
    const int row = qw * 32 + l31;  // block-local q row
    {
      const u16* qp = qn + (size_t)(b * 2048 + qt * 128 + row) * 2048 + h * 64 + l5 * 8;
#pragma unroll
      for (int ki = 0; ki < 4; ++ki) qf[ki] = *(const s16x8*)(qp + ki * 16);
#pragma unroll
      for (int r = 0; r < 16; ++r) { O0[r] = 0.f; O1[r] = 0.f; }
      lst = 0.f;
    }
    issue(0);
    stash();
    __syncthreads();
    const int nss = qt + 1;
    for (int i = 0; i < nss; ++i) {
      const int T = 2 * i + half;  // my KV tile
      const char* sK = sKV[T & 3][0];
      const char* sV = sKV[T & 3][1];
      if (i + 1 < nss) issue(2 * i + 2);
      // ---- QK^T (keys sigma-permuted)
      f32x16 sc0, sc1;
#pragma unroll
      for (int r = 0; r < 16; ++r) { sc0[r] = 0.f; sc1[r] = 0.f; }
      __builtin_amdgcn_s_setprio(1);
#pragma unroll
      for (int ki = 0; ki < 4; ++ki) {
        const int cb = ki * 32 + l5 * 16;
        const int r0 = l31, r1 = 32 + l31;
        s16x8 a0 = *(const s16x8*)(sK + r0 * 128 + (cb ^ ((r0 & 7) << 4)));
        s16x8 a1 = *(const s16x8*)(sK + r1 * 128 + (cb ^ ((r1 & 7) << 4)));
        sc0 = __builtin_amdgcn_mfma_f32_32x32x16_bf16(a0, qf[ki], sc0, 0, 0, 0);
        sc1 = __builtin_amdgcn_mfma_f32_32x32x16_bf16(a1, qf[ki], sc1, 0, 0, 0);
      }
      __builtin_amdgcn_s_setprio(0);
      // ---- causal mask (sigma-inverse key index); last superstep only
      if (T >= 2 * qt) {
        const int qrow = qt * 128 + row;
        const int kb0 = T * 64 + 8 * l5;
#pragma unroll
        for (int r = 0; r < 16; ++r) {
          const int klocal = 16 * (r >> 3) + 4 * ((r >> 2) & 1) + (r & 3);
          if (kb0 + klocal > qrow) sc0[r] = -1e30f;
          if (kb0 + 32 + klocal > qrow) sc1[r] = -1e30f;
        }
      }
      // ---- fixed-scale softmax: P = exp2(score)
      float rs = 0.f;
      u32 pk0[4][2], pk1[4][2];
#pragma unroll
      for (int g = 0; g < 4; ++g) {
        float a0 = EXP2(sc0[4*g+0]), a1 = EXP2(sc0[4*g+1]);
        float a2 = EXP2(sc0[4*g+2]), a3 = EXP2(sc0[4*g+3]);
        float b0 = EXP2(sc1[4*g+0]), b1 = EXP2(sc1[4*g+1]);
        float b2 = EXP2(sc1[4*g+2]), b3 = EXP2(sc1[4*g+3]);
        rs += ((a0 + a1) + (a2 + a3)) + ((b0 + b1) + (b2 + b3));
        pk0[g][0] = cvtpk(a0, a1);
        pk0[g][1] = cvtpk(a2, a3);
        pk1[g][0] = cvtpk(b0, b1);
        pk1[g][1] = cvtpk(b2, b3);
      }
      rs += __shfl_xor(rs, 32, 64);
      lst += rs;
      // ---- PV: P already in B-frag layout; zero shuffles
#define PV_STEP(PK, GB, KB)                                                   \
      {                                                                       \
        u32x4 wv_ = { PK[GB][0], PK[GB][1], PK[GB+1][0], PK[GB+1][1] };       \
        s16x8 pb = __builtin_bit_cast(s16x8, wv_);                            \
        const int cb = (KB) * 32 + l5 * 16;                                   \
        const int rv0 = l31, rv1 = 32 + l31;                                  \
        s16x8 v0 = *(const s16x8*)(sV + rv0 * 128 + (cb ^ ((rv0 & 7) << 4))); \
        s16x8 v1 = *(const s16x8*)(sV + rv1 * 128 + (cb ^ ((rv1 & 7) << 4))); \
        __builtin_amdgcn_s_setprio(1);                                        \
        O0 = __builtin_amdgcn_mfma_f32_32x32x16_bf16(v0, pb, O0, 0, 0, 0);    \
        O1 = __builtin_amdgcn_mfma_f32_32x32x16_bf16(v1, pb, O1, 0, 0, 0);    \
        __builtin_amdgcn_s_setprio(0);                                        \
      }
      PV_STEP(pk0, 0, 0)
      PV_STEP(pk0, 2, 1)
      PV_STEP(pk1, 0, 2)
      PV_STEP(pk1, 2, 3)
#undef PV_STEP
      if (i + 1 < nss) stash();
      __syncthreads();
    }
    // ---- merge the two halves' partial (O, lst), then store
    if (half == 1) {
#pragma unroll
      for (int g = 0; g < 4; ++g)
#pragma unroll
        for (int j = 0; j < 4; ++j) {
          const int d = 8 * g + 4 * l5 + j;
          mO[row * 65 + d] = O0[4*g+j];
          mO[row * 65 + 32 + d] = O1[4*g+j];
        }
      if (l5 == 0) mL[row] = lst;
    }
    __syncthreads();
    if (half == 0) {
      const float inv = 1.0f / (lst + mL[row]);
      const size_t rowoff = (size_t)(b * 2048 + qt * 128 + row) * 2048 + h * 64;
#pragma unroll
      for (int g = 0; g < 4; ++g) {
        const int d0 = 8 * g + 4 * l5;
        u16x4 o0 = { f2bf((O0[4*g+0] + mO[row*65+d0+0]) * inv),
                     f2bf((O0[4*g+1] + mO[row*65+d0+1]) * inv),
                     f2bf((O0[4*g+2] + mO[row*65+d0+2]) * inv),
                     f2bf((O0[4*g+3] + mO[row*65+d0+3]) * inv) };
        *(u16x4*)(aout + rowoff + d0) = o0;
        u16x4 o1 = { f2bf((O1[4*g+0] + mO[row*65+32+d0+0]) * inv),
                     f2bf((O1[4*g+1] + mO[row*65+32+d0+1]) * inv),
                     f2bf((O1[4*g+2] + mO[row*65+32+d0+2]) * inv),
                     f2bf((O1[4*g+3] + mO[row*65+32+d0+3]) * inv) };
        *(u16x4*)(aout + rowoff + 32 + d0) = o1;
      }
    }
    __syncthreads();  // merge reads done before next member's staging
  }
}

extern "C" void kernel_launch(void* const* d_in, const int* in_sizes, int n_in,
                              void* d_out, int out_size, void* d_ws, size_t ws_size,
                              hipStream_t stream) {
  (void)in_sizes; (void)n_in; (void)out_size; (void)ws_size;
  const float* x    = (const float*)d_in[0];
  const float* wq   = (const float*)d_in[1];
  const float* wk   = (const float*)d_in[2];
  const float* wv   = (const float*)d_in[3];
  const float* wo   = (const float*)d_in[4];
  const float* qs   = (const float*)d_in[5];
  const float* ksc  = (const float*)d_in[6];
  const float* cosb = (const float*)d_in[7];
  const float* sinb = (const float*)d_in[8];
  float* out = (float*)d_out;
  char* ws = (char*)d_ws;
  u16* xbf   = (u16*)(ws);                 // 16 MB  4096x2048 bf16
  u16* wqkvt = (u16*)(ws + 16777216);      // 12 MB  3072x2048 bf16 (W^T)
  u16* wot   = (u16*)(ws + 29360128);      // 8 MB   2048x2048 bf16 (Wo^T)
  u16* qkv   = (u16*)(ws + 37748736);      // 24 MB  4096x3072 bf16
  u16* qn    = (u16*)(ws + 62914560);      // 16 MB  4096x2048 bf16
  u16* kn    = (u16*)(ws + 79691776);      // 4 MB   4096x512 bf16
  u16* vt    = (u16*)(ws + 83886080);      // 4 MB   (b,kv,d) x 2048 bf16
  u16* aout  = (u16*)(ws + 88080384);      // 16 MB  4096x2048 bf16

  k_conv_x<<<8192, 256, 0, stream>>>(x, xbf);
  k_transw<<<dim3(32, 32), 256, 0, stream>>>(wq, wqkvt, 2048, 2048);
  k_transw<<<dim3(8, 32), 256, 0, stream>>>(wk, wqkvt + (size_t)2048 * 2048, 512, 2048);
  k_transw<<<dim3(8, 32), 256, 0, stream>>>(wv, wqkvt + (size_t)2560 * 2048, 512, 2048);
  k_transw<<<dim3(32, 32), 256, 0, stream>>>(wo, wot, 2048, 2048);
  // QKV: 128x192 tiles -> 32x16 = 512 blocks, 2 blocks/CU (80KB LDS), exact fill
  k_gemm8<128, 192, u16><<<512, 512, 0, stream>>>(xbf, wqkvt, qkv, MROWS, NQKV, 2048, 16);
  k_normrope<<<40960, 256, 0, stream>>>(qkv, qn, kn, qs, ksc, cosb, sinb);
  k_vtrans<<<dim3(32, 16), 256, 0, stream>>>(qkv, vt);
  k_attn<<<512, 512, 0, stream>>>(qn, kn, vt, aout);
  // OUT: 128x128 tiles -> 32x16 = 512 blocks, 2 blocks/CU (64KB LDS), exact fill
  k_gemm8<128, 128, float><<<512, 512, 0, stream>>>(aout, wot, out, MROWS, DMODEL, 2048, 16);
}

// Round 18
// 193.337 us; speedup vs baseline: 1.4577x; 1.0747x over previous
//
#include <hip/hip_runtime.h>
#include <hip/hip_bf16.h>

typedef float f32x4 __attribute__((ext_vector_type(4)));
typedef float f32x16 __attribute__((ext_vector_type(16)));
typedef short s16x8 __attribute__((ext_vector_type(8)));
typedef unsigned short u16;
typedef unsigned short u16x8 __attribute__((ext_vector_type(8)));
typedef unsigned short u16x4 __attribute__((ext_vector_type(4)));
typedef unsigned int u32;
typedef unsigned int u32x4 __attribute__((ext_vector_type(4)));

#define MROWS 4096   // B*S
#define NQKV  3072   // NH*HD + 2*NKV*HD
#define DMODEL 2048

#define EXP2(x) __builtin_amdgcn_exp2f(x)

__device__ __forceinline__ u16 f2bf(float f) {
  __hip_bfloat16 h = __float2bfloat16(f);
  return __builtin_bit_cast(u16, h);
}
__device__ __forceinline__ float bf2f(u16 u) {
  __hip_bfloat16 h = __builtin_bit_cast(__hip_bfloat16, u);
  return __bfloat162float(h);
}

// HW packed f32->bf16 (RNE): dst.lo = bf16(a), dst.hi = bf16(b)
__device__ __forceinline__ u32 cvtpk(float a, float b) {
  u32 r;
  asm("v_cvt_pk_bf16_f32 %0, %1, %2" : "=v"(r) : "v"(a), "v"(b));
  return r;
}

typedef __attribute__((address_space(3))) unsigned int lds_u32_t;
typedef const __attribute__((address_space(1))) unsigned int glb_u32_t;
__device__ __forceinline__ void gload_lds16(const void* g, void* l) {
  __builtin_amdgcn_global_load_lds((glb_u32_t*)g, (lds_u32_t*)l, 16, 0, 0);
}

// ---------------- fp32 -> bf16 convert (x), 8 elems/thread ----------------
__global__ __launch_bounds__(256) void k_conv_x(const float* __restrict__ x, u16* __restrict__ o) {
  size_t i = ((size_t)blockIdx.x * 256 + threadIdx.x) * 8;
  float4 v0 = *(const float4*)(x + i);
  float4 v1 = *(const float4*)(x + i + 4);
  u32x4 r = { cvtpk(v0.x, v0.y), cvtpk(v0.z, v0.w), cvtpk(v1.x, v1.y), cvtpk(v1.z, v1.w) };
  *(u32x4*)(o + i) = r;
}

// ------- transpose + convert: src (K x N) f32 -> dst (N x K) bf16 -------
__global__ __launch_bounds__(256) void k_transw(const float* __restrict__ src, u16* __restrict__ dst,
                                                int N, int K) {
  __shared__ u16 t[64][68];
  int n0 = blockIdx.x * 64, k0 = blockIdx.y * 64;
  int tid = threadIdx.x;
#pragma unroll
  for (int r = 0; r < 4; ++r) {
    int k = r * 16 + (tid >> 4);
    int n = (tid & 15) * 4;
    float4 v = *(const float4*)(src + (size_t)(k0 + k) * N + n0 + n);
    t[n + 0][k] = f2bf(v.x);
    t[n + 1][k] = f2bf(v.y);
    t[n + 2][k] = f2bf(v.z);
    t[n + 3][k] = f2bf(v.w);
  }
  __syncthreads();
#pragma unroll
  for (int r = 0; r < 4; ++r) {
    int n = r * 16 + (tid >> 4);
    int k = (tid & 15) * 4;
    u16x4 o = { t[n][k], t[n][k + 1], t[n][k + 2], t[n][k + 3] };
    *(u16x4*)(dst + (size_t)(n0 + n) * K + k0 + k) = o;
  }
}

// ------ bf16 GEMM v5: 2-phase skeleton with 3-chunk-ahead staging ------
template <int BM, int BN, typename OutT>
__global__ __launch_bounds__(512, 2)
void k_gemm8(const u16* __restrict__ A, const u16* __restrict__ Bt,
             OutT* __restrict__ C, int M, int N, int K, int nbx) {
  static_assert(BM == 128, "A staging assumes one full 512x16B round");
  constexpr int WM = 2, WN = 4;
  constexpr int MF = BM / 16 / WM;   // 4
  constexpr int NF = BN / 16 / WN;   // 2 (BN=128), 3 (BN=192), 4 (BN=256)
  __shared__ u16 sA[2][2][BM][32];
  __shared__ u16 sB[2][2][BN][32];
  const int nwg = gridDim.x;
  const int chunk = nwg >> 3;
  const int wg = (blockIdx.x & 7) * chunk + (blockIdx.x >> 3);
  const int m0 = (wg / nbx) * BM, n0 = (wg % nbx) * BN;
  const int tid = threadIdx.x;
  const int l = tid & 63;
  const int lo = l & 15, hi = l >> 4;
  const int wid = tid >> 6;
  const int wm = wid >> 2, wn = wid & 3;
  const int nkt = K >> 6;  // 64-wide K tiles

  f32x4 acc[MF][NF] = {};

  auto STAGE = [&](int ks, int t) {
    const int buf = t & 1;
    {
      const int D = tid * 16;
      const int row = D >> 6;
      const int srcb = (D & 63) ^ (((row >> 1) & 3) << 4);
      gload_lds16((const char*)(A + (size_t)(m0 + row) * K + t * 64 + ks * 32) + srcb,
                  (char*)(&sA[buf][ks][0][0]) + D);
    }
#pragma unroll
    for (int i = 0; i < 2; ++i) {
      const int u = i * 512 + tid;
      if (u < BN * 4) {
        const int D = u * 16;
        const int row = D >> 6;
        const int srcb = (D & 63) ^ (((row >> 1) & 3) << 4);
        gload_lds16((const char*)(Bt + (size_t)(n0 + row) * K + t * 64 + ks * 32) + srcb,
                    (char*)(&sB[buf][ks][0][0]) + D);
      }
    }
  };

  auto WAITVM = [&]() {  // leave exactly TWO phases' own issues in flight
    if constexpr (BN == 192) {
      if (wid < 4) asm volatile("s_waitcnt vmcnt(6)" ::: "memory");
      else         asm volatile("s_waitcnt vmcnt(4)" ::: "memory");
    } else if constexpr (BN == 256) {
      asm volatile("s_waitcnt vmcnt(6)" ::: "memory");
    } else {  // BN == 128
      asm volatile("s_waitcnt vmcnt(4)" ::: "memory");
    }
  };

  auto PHASE = [&](int buf, int ks, bool st, int st_ks, int st_t) {
    s16x8 a[MF], b[NF];
#pragma unroll
    for (int mf = 0; mf < MF; ++mf) {
      const int row = wm * (MF * 16) + mf * 16 + lo;
      a[mf] = *(const s16x8*)((const char*)(&sA[buf][ks][0][0]) + row * 64 +
                              ((hi * 16) ^ (((row >> 1) & 3) << 4)));
    }
#pragma unroll
    for (int nf = 0; nf < NF; ++nf) {
      const int row = wn * (NF * 16) + nf * 16 + lo;
      b[nf] = *(const s16x8*)((const char*)(&sB[buf][ks][0][0]) + row * 64 +
                              ((hi * 16) ^ (((row >> 1) & 3) << 4)));
    }
    if (st) STAGE(st_ks, st_t);
    __builtin_amdgcn_sched_barrier(0);
    __builtin_amdgcn_s_barrier();
    asm volatile("s_waitcnt lgkmcnt(0)" ::: "memory");
    __builtin_amdgcn_sched_barrier(0);
    __builtin_amdgcn_s_setprio(1);
#pragma unroll
    for (int mf = 0; mf < MF; ++mf)
#pragma unroll
      for (int nf = 0; nf < NF; ++nf)
        acc[mf][nf] = __builtin_amdgcn_mfma_f32_16x16x32_bf16(a[mf], b[nf], acc[mf][nf], 0, 0, 0);
    __builtin_amdgcn_s_setprio(0);
    if (st) WAITVM();
    else    asm volatile("s_waitcnt vmcnt(0)" ::: "memory");
    __builtin_amdgcn_sched_barrier(0);
    __builtin_amdgcn_s_barrier();
  };

  STAGE(0, 0);
  STAGE(1, 0);
  STAGE(0, 1);
  WAITVM();
  __builtin_amdgcn_s_barrier();

  for (int t = 0; t < nkt; ++t) {
    const int buf = t & 1;
    PHASE(buf, 0, t + 1 < nkt, 1, t + 1);
    PHASE(buf, 1, t + 2 < nkt, 0, t + 2);
  }

#pragma unroll
  for (int mf = 0; mf < MF; ++mf)
#pragma unroll
    for (int nf = 0; nf < NF; ++nf)
#pragma unroll
      for (int r = 0; r < 4; ++r) {
        const int row = m0 + wm * (MF * 16) + mf * 16 + hi * 4 + r;
        const int col = n0 + wn * (NF * 16) + nf * 16 + lo;
        if constexpr (__is_same(OutT, float)) C[(size_t)row * N + col] = acc[mf][nf][r];
        else                                  C[(size_t)row * N + col] = f2bf(acc[mf][nf][r]);
      }
}

// ------- fused RMSNorm + RoPE v2: 8 elems/lane, 8 head-vectors/wave -------
// lane i: vector g=i>>3 of the wave's 8, elems 8*(i&7)..+7 (u16x8, 16B/lane).
// RMS reduce over the 8-lane group (shfl_xor 1,2,4); RoPE partner = lane^4.
__global__ __launch_bounds__(256) void k_normrope(const u16* __restrict__ qkv, u16* __restrict__ qn,
                                                  u16* __restrict__ kn, const float* __restrict__ qs,
                                                  const float* __restrict__ ksc,
                                                  const float* __restrict__ cosb,
                                                  const float* __restrict__ sinb) {
  const int i = threadIdx.x & 63;
  const int sub = i & 7;
  const int j = (blockIdx.x * 4 + (threadIdx.x >> 6)) * 8 + (i >> 3);  // vector id
  const bool isQ = j < MROWS * 32;
  int m, head, incol;
  if (isQ) { m = j >> 5; head = j & 31; incol = head * 64; }
  else     { int j2 = j - MROWS * 32; m = j2 >> 3; head = j2 & 7; incol = 2048 + head * 64; }
  const u16x8 raw = *(const u16x8*)(qkv + (size_t)m * NQKV + incol + sub * 8);
  float f[8];
#pragma unroll
  for (int e = 0; e < 8; ++e) f[e] = bf2f(raw[e]);
  float ss = 0.f;
#pragma unroll
  for (int e = 0; e < 8; ++e) ss += f[e] * f[e];
  ss += __shfl_xor(ss, 1, 64);
  ss += __shfl_xor(ss, 2, 64);
  ss += __shfl_xor(ss, 4, 64);
  const float inv = rsqrtf(ss * (1.0f / 64.0f) + 1e-6f);
  const float* sc = isQ ? qs : ksc;
  float4 s0 = *(const float4*)(sc + sub * 8);
  float4 s1 = *(const float4*)(sc + sub * 8 + 4);
  float nx[8];
  nx[0] = f[0] * inv * s0.x; nx[1] = f[1] * inv * s0.y;
  nx[2] = f[2] * inv * s0.z; nx[3] = f[3] * inv * s0.w;
  nx[4] = f[4] * inv * s1.x; nx[5] = f[5] * inv * s1.y;
  nx[6] = f[6] * inv * s1.z; nx[7] = f[7] * inv * s1.w;
  const float sgn = (sub < 4) ? -1.f : 1.f;
  float rot[8];
#pragma unroll
  for (int e = 0; e < 8; ++e) rot[e] = sgn * __shfl_xor(nx[e], 4, 64);
  const int s = m & 2047;
  float4 c0 = *(const float4*)(cosb + s * 64 + sub * 8);
  float4 c1 = *(const float4*)(cosb + s * 64 + sub * 8 + 4);
  float4 n0 = *(const float4*)(sinb + s * 64 + sub * 8);
  float4 n1 = *(const float4*)(sinb + s * 64 + sub * 8 + 4);
  float outv[8];
  outv[0] = nx[0] * c0.x + rot[0] * n0.x; outv[1] = nx[1] * c0.y + rot[1] * n0.y;
  outv[2] = nx[2] * c0.z + rot[2] * n0.z; outv[3] = nx[3] * c0.w + rot[3] * n0.w;
  outv[4] = nx[4] * c1.x + rot[4] * n1.x; outv[5] = nx[5] * c1.y + rot[5] * n1.y;
  outv[6] = nx[6] * c1.z + rot[6] * n1.z; outv[7] = nx[7] * c1.w + rot[7] * n1.w;
  if (isQ) {
    const float qsc = 0.125f * 1.44269504088896f;  // fold 1/sqrt(HD), log2(e)
#pragma unroll
    for (int e = 0; e < 8; ++e) outv[e] *= qsc;
    u32x4 r = { cvtpk(outv[0], outv[1]), cvtpk(outv[2], outv[3]),
                cvtpk(outv[4], outv[5]), cvtpk(outv[6], outv[7]) };
    *(u32x4*)(qn + (size_t)m * 2048 + incol + sub * 8) = r;
  } else {
    u32x4 r = { cvtpk(outv[0], outv[1]), cvtpk(outv[2], outv[3]),
                cvtpk(outv[4], outv[5]), cvtpk(outv[6], outv[7]) };
    *(u32x4*)(kn + (size_t)m * 512 + head * 64 + sub * 8) = r;
  }
}

// ------- V transpose: QKV v-region -> vt[(b*8+kv)*64 + d][s] -------
__global__ __launch_bounds__(256) void k_vtrans(const u16* __restrict__ qkv, u16* __restrict__ vt) {
  __shared__ u16 t[64][68];
  int s0 = blockIdx.x * 64;
  int bk = blockIdx.y;  // b*8 + kv
  int tid = threadIdx.x;
#pragma unroll
  for (int r = 0; r < 4; ++r) {
    int s = r * 16 + (tid >> 4);
    int d = (tid & 15) * 4;
    u16x4 v = *(const u16x4*)(qkv + (size_t)((bk >> 3) * 2048 + s0 + s) * NQKV + 2560 + (bk & 7) * 64 + d);
    t[d + 0][s] = v[0];
    t[d + 1][s] = v[1];
    t[d + 2][s] = v[2];
    t[d + 3][s] = v[3];
  }
  __syncthreads();
#pragma unroll
  for (int r = 0; r < 4; ++r) {
    int d = r * 16 + (tid >> 4);
    int sl = (tid & 15) * 4;
    u16x4 o = { t[d][sl], t[d][sl + 1], t[d][sl + 2], t[d][sl + 3] };
    *(u16x4*)(vt + (size_t)(bk * 64 + d) * 2048 + s0 + sl) = o;
  }
}

// ------- causal flash attention v8b (proven) -------
__global__ __launch_bounds__(512, 2) void k_attn(const u16* __restrict__ qn, const u16* __restrict__ kn,
                                                 const u16* __restrict__ vt, u16* __restrict__ aout) {
  __shared__ char sKV[4][2][64 * 128];  // [buf][K|V][row][128B], 64KB
  float* mO = (float*)&sKV[0][0][0];    // merge buffer alias: 128 x 65 f32
  float* mL = mO + 128 * 65;            // + 128 f32 lst
  const int bid = blockIdx.x;           // 512 blocks
  const int kvh = bid & 7;              // XCD-locality
  const int b = (bid >> 3) & 1;
  const int hsub = (bid >> 4) & 3;
  const int p = bid >> 6;               // 0..7
  const int h = kvh * 4 + hsub;
  const int tid = threadIdx.x, l = tid & 63;
  const int w = tid >> 6, qw = w & 3, half = w >> 2;
  const int l31 = l & 31, l5 = l >> 5;
  const int qtA = 15 - p, qtB = p;
  const u16* kbase = kn + (size_t)(b * 2048) * 512 + kvh * 64;
  const u16* vbase = vt + (size_t)((b * 8 + kvh) * 64) * 2048;
  const int st = tid >> 8;
  const int stid = tid & 255;
  const int srow = stid >> 3;
  const int scol = (stid & 7) * 8;
  const int sg_t = srow >> 4, sg_h = (srow >> 3) & 1, sg_j = srow & 7;
  const int krow0 = 32 * (sg_t >> 1) + 8 * ((sg_t & 1) * 2 + (sg_j >> 2)) + 4 * sg_h + (sg_j & 3);

  u16x8 krg0, krg1, vrg0, vrg1;
  int stbuf = 0;
  auto issue = [&](int baset) {
    const int tile = baset + st;
    const int kv0 = tile * 64;
    stbuf = tile & 3;
    krg0 = *(const u16x8*)(kbase + (size_t)(kv0 + srow) * 512 + scol);
    krg1 = *(const u16x8*)(kbase + (size_t)(kv0 + srow + 32) * 512 + scol);
    vrg0 = *(const u16x8*)(vbase + (size_t)srow * 2048 + kv0 + scol);
    vrg1 = *(const u16x8*)(vbase + (size_t)(srow + 32) * 2048 + kv0 + scol);
  };
  auto stash = [&]() {
    char* sK = sKV[stbuf][0];
    char* sV = sKV[stbuf][1];
    const int cb = scol * 2;
    const int k0_ = krow0, k1_ = krow0 + 32;
    *(u16x8*)(sK + k0_ * 128 + (cb ^ ((k0_ & 7) << 4))) = krg0;
    *(u16x8*)(sK + k1_ * 128 + (cb ^ ((k1_ & 7) << 4))) = krg1;
    const int r0 = srow, r1 = srow + 32;
    *(u16x8*)(sV + r0 * 128 + (cb ^ ((r0 & 7) << 4))) = vrg0;
    *(u16x8*)(sV + r1 * 128 + (cb ^ ((r1 & 7) << 4))) = vrg1;
  };

  s16x8 qf[4];
  f32x16 O0, O1;
  float lst;

  for (int mem = 0; mem < 2; ++mem) {
    const int qt = mem ? qtB : qtA;
    const int row = qw * 32 + l31;  // block-local q row
    {
      const u16* qp = qn + (size_t)(b * 2048 + qt * 128 + row) * 2048 + h * 64 + l5 * 8;
#pragma unroll
      for (int ki = 0; ki < 4; ++ki) qf[ki] = *(const s16x8*)(qp + ki * 16);
#pragma unroll
      for (int r = 0; r < 16; ++r) { O0[r] = 0.f; O1[r] = 0.f; }
      lst = 0.f;
    }
    issue(0);
    stash();
    __syncthreads();
    const int nss = qt + 1;
    for (int i = 0; i < nss; ++i) {
      const int T = 2 * i + half;  // my KV tile
      const char* sK = sKV[T & 3][0];
      const char* sV = sKV[T & 3][1];
      if (i + 1 < nss) issue(2 * i + 2);
      // ---- QK^T (keys sigma-permuted)
      f32x16 sc0, sc1;
#pragma unroll
      for (int r = 0; r < 16; ++r) { sc0[r] = 0.f; sc1[r] = 0.f; }
      __builtin_amdgcn_s_setprio(1);
#pragma unroll
      for (int ki = 0; ki < 4; ++ki) {
        const int cb = ki * 32 + l5 * 16;
        const int r0 = l31, r1 = 32 + l31;
        s16x8 a0 = *(const s16x8*)(sK + r0 * 128 + (cb ^ ((r0 & 7) << 4)));
        s16x8 a1 = *(const s16x8*)(sK + r1 * 128 + (cb ^ ((r1 & 7) << 4)));
        sc0 = __builtin_amdgcn_mfma_f32_32x32x16_bf16(a0, qf[ki], sc0, 0, 0, 0);
        sc1 = __builtin_amdgcn_mfma_f32_32x32x16_bf16(a1, qf[ki], sc1, 0, 0, 0);
      }
      __builtin_amdgcn_s_setprio(0);
      // ---- causal mask (sigma-inverse key index); last superstep only
      if (T >= 2 * qt) {
        const int qrow = qt * 128 + row;
        const int kb0 = T * 64 + 8 * l5;
#pragma unroll
        for (int r = 0; r < 16; ++r) {
          const int klocal = 16 * (r >> 3) + 4 * ((r >> 2) & 1) + (r & 3);
          if (kb0 + klocal > qrow) sc0[r] = -1e30f;
          if (kb0 + 32 + klocal > qrow) sc1[r] = -1e30f;
        }
      }
      // ---- fixed-scale softmax: P = exp2(score)
      float rs = 0.f;
      u32 pk0[4][2], pk1[4][2];
#pragma unroll
      for (int g = 0; g < 4; ++g) {
        float a0 = EXP2(sc0[4*g+0]), a1 = EXP2(sc0[4*g+1]);
        float a2 = EXP2(sc0[4*g+2]), a3 = EXP2(sc0[4*g+3]);
        float b0 = EXP2(sc1[4*g+0]), b1 = EXP2(sc1[4*g+1]);
        float b2 = EXP2(sc1[4*g+2]), b3 = EXP2(sc1[4*g+3]);
        rs += ((a0 + a1) + (a2 + a3)) + ((b0 + b1) + (b2 + b3));
        pk0[g][0] = cvtpk(a0, a1);
        pk0[g][1] = cvtpk(a2, a3);
        pk1[g][0] = cvtpk(b0, b1);
        pk1[g][1] = cvtpk(b2, b3);
      }
      rs += __shfl_xor(rs, 32, 64);
      lst += rs;
      // ---- PV: P already in B-frag layout; zero shuffles
#define PV_STEP(PK, GB, KB)                                                   \
      {                                                                       \
        u32x4 wv_ = { PK[GB][0], PK[GB][1], PK[GB+1][0], PK[GB+1][1] };       \
        s16x8 pb = __builtin_bit_cast(s16x8, wv_);                            \
        const int cb = (KB) * 32 + l5 * 16;                                   \
        const int rv0 = l31, rv1 = 32 + l31;                                  \
        s16x8 v0 = *(const s16x8*)(sV + rv0 * 128 + (cb ^ ((rv0 & 7) << 4))); \
        s16x8 v1 = *(const s16x8*)(sV + rv1 * 128 + (cb ^ ((rv1 & 7) << 4))); \
        __builtin_amdgcn_s_setprio(1);                                        \
        O0 = __builtin_amdgcn_mfma_f32_32x32x16_bf16(v0, pb, O0, 0, 0, 0);    \
        O1 = __builtin_amdgcn_mfma_f32_32x32x16_bf16(v1, pb, O1, 0, 0, 0);    \
        __builtin_amdgcn_s_setprio(0);                                        \
      }
      PV_STEP(pk0, 0, 0)
      PV_STEP(pk0, 2, 1)
      PV_STEP(pk1, 0, 2)
      PV_STEP(pk1, 2, 3)
#undef PV_STEP
      if (i + 1 < nss) stash();
      __syncthreads();
    }
    // ---- merge the two halves' partial (O, lst), then store
    if (half == 1) {
#pragma unroll
      for (int g = 0; g < 4; ++g)
#pragma unroll
        for (int j = 0; j < 4; ++j) {
          const int d = 8 * g + 4 * l5 + j;
          mO[row * 65 + d] = O0[4*g+j];
          mO[row * 65 + 32 + d] = O1[4*g+j];
        }
      if (l5 == 0) mL[row] = lst;
    }
    __syncthreads();
    if (half == 0) {
      const float inv = 1.0f / (lst + mL[row]);
      const size_t rowoff = (size_t)(b * 2048 + qt * 128 + row) * 2048 + h * 64;
#pragma unroll
      for (int g = 0; g < 4; ++g) {
        const int d0 = 8 * g + 4 * l5;
        u16x4 o0 = { f2bf((O0[4*g+0] + mO[row*65+d0+0]) * inv),
                     f2bf((O0[4*g+1] + mO[row*65+d0+1]) * inv),
                     f2bf((O0[4*g+2] + mO[row*65+d0+2]) * inv),
                     f2bf((O0[4*g+3] + mO[row*65+d0+3]) * inv) };
        *(u16x4*)(aout + rowoff + d0) = o0;
        u16x4 o1 = { f2bf((O1[4*g+0] + mO[row*65+32+d0+0]) * inv),
                     f2bf((O1[4*g+1] + mO[row*65+32+d0+1]) * inv),
                     f2bf((O1[4*g+2] + mO[row*65+32+d0+2]) * inv),
                     f2bf((O1[4*g+3] + mO[row*65+32+d0+3]) * inv) };
        *(u16x4*)(aout + rowoff + 32 + d0) = o1;
      }
    }
    __syncthreads();  // merge reads done before next member's staging
  }
}

extern "C" void kernel_launch(void* const* d_in, const int* in_sizes, int n_in,
                              void* d_out, int out_size, void* d_ws, size_t ws_size,
                              hipStream_t stream) {
  (void)in_sizes; (void)n_in; (void)out_size; (void)ws_size;
  const float* x    = (const float*)d_in[0];
  const float* wq   = (const float*)d_in[1];
  const float* wk   = (const float*)d_in[2];
  const float* wv   = (const float*)d_in[3];
  const float* wo   = (const float*)d_in[4];
  const float* qs   = (const float*)d_in[5];
  const float* ksc  = (const float*)d_in[6];
  const float* cosb = (const float*)d_in[7];
  const float* sinb = (const float*)d_in[8];
  float* out = (float*)d_out;
  char* ws = (char*)d_ws;
  u16* xbf   = (u16*)(ws);                 // 16 MB  4096x2048 bf16
  u16* wqkvt = (u16*)(ws + 16777216);      // 12 MB  3072x2048 bf16 (W^T)
  u16* wot   = (u16*)(ws + 29360128);      // 8 MB   2048x2048 bf16 (Wo^T)
  u16* qkv   = (u16*)(ws + 37748736);      // 24 MB  4096x3072 bf16
  u16* qn    = (u16*)(ws + 62914560);      // 16 MB  4096x2048 bf16
  u16* kn    = (u16*)(ws + 79691776);      // 4 MB   4096x512 bf16
  u16* vt    = (u16*)(ws + 83886080);      // 4 MB   (b,kv,d) x 2048 bf16
  u16* aout  = (u16*)(ws + 88080384);      // 16 MB  4096x2048 bf16

  k_conv_x<<<4096, 256, 0, stream>>>(x, xbf);
  k_transw<<<dim3(32, 32), 256, 0, stream>>>(wq, wqkvt, 2048, 2048);
  k_transw<<<dim3(8, 32), 256, 0, stream>>>(wk, wqkvt + (size_t)2048 * 2048, 512, 2048);
  k_transw<<<dim3(8, 32), 256, 0, stream>>>(wv, wqkvt + (size_t)2560 * 2048, 512, 2048);
  k_transw<<<dim3(32, 32), 256, 0, stream>>>(wo, wot, 2048, 2048);
  // QKV: 128x192 tiles -> 32x16 = 512 blocks, 2 blocks/CU (80KB LDS), exact fill
  k_gemm8<128, 192, u16><<<512, 512, 0, stream>>>(xbf, wqkvt, qkv, MROWS, NQKV, 2048, 16);
  k_normrope<<<5120, 256, 0, stream>>>(qkv, qn, kn, qs, ksc, cosb, sinb);
  k_vtrans<<<dim3(32, 16), 256, 0, stream>>>(qkv, vt);
  k_attn<<<512, 512, 0, stream>>>(qn, kn, vt, aout);
  // OUT: 128x128 tiles -> 32x16 = 512 blocks, 2 blocks/CU (64KB LDS), exact fill
  k_gemm8<128, 128, float><<<512, 512, 0, stream>>>(aout, wot, out, MROWS, DMODEL, 2048, 16);
}

// Round 19
// 184.163 us; speedup vs baseline: 1.5303x; 1.0498x over previous
//
#include <hip/hip_runtime.h>
#include <hip/hip_bf16.h>

typedef float f32x4 __attribute__((ext_vector_type(4)));
typedef float f32x16 __attribute__((ext_vector_type(16)));
typedef short s16x8 __attribute__((ext_vector_type(8)));
typedef unsigned short u16;
typedef unsigned short u16x8 __attribute__((ext_vector_type(8)));
typedef unsigned short u16x4 __attribute__((ext_vector_type(4)));
typedef unsigned int u32;
typedef unsigned int u32x4 __attribute__((ext_vector_type(4)));

#define MROWS 4096   // B*S
#define NQKV  3072   // NH*HD + 2*NKV*HD
#define DMODEL 2048

#define EXP2(x) __builtin_amdgcn_exp2f(x)

__device__ __forceinline__ u16 f2bf(float f) {
  __hip_bfloat16 h = __float2bfloat16(f);
  return __builtin_bit_cast(u16, h);
}
__device__ __forceinline__ float bf2f(u16 u) {
  __hip_bfloat16 h = __builtin_bit_cast(__hip_bfloat16, u);
  return __bfloat162float(h);
}

// HW packed f32->bf16 (RNE): dst.lo = bf16(a), dst.hi = bf16(b)
__device__ __forceinline__ u32 cvtpk(float a, float b) {
  u32 r;
  asm("v_cvt_pk_bf16_f32 %0, %1, %2" : "=v"(r) : "v"(a), "v"(b));
  return r;
}

typedef __attribute__((address_space(3))) unsigned int lds_u32_t;
typedef const __attribute__((address_space(1))) unsigned int glb_u32_t;
__device__ __forceinline__ void gload_lds16(const void* g, void* l) {
  __builtin_amdgcn_global_load_lds((glb_u32_t*)g, (lds_u32_t*)l, 16, 0, 0);
}

// ---- k_prep: fused {x fp32->bf16 convert} + {4x weight transpose-convert} ----
// bid < 4096: conv (8 elems/thread). Else transpose 64x64 tile of one of
// wq/wk/wv/wo (all K=2048): dst(N x K) bf16 from src(K x N) f32.
__global__ __launch_bounds__(256) void k_prep(const float* __restrict__ x,
                                              const float* __restrict__ wq,
                                              const float* __restrict__ wk,
                                              const float* __restrict__ wv,
                                              const float* __restrict__ wo,
                                              u16* __restrict__ xbf,
                                              u16* __restrict__ wqkvt,
                                              u16* __restrict__ wot) {
  __shared__ u16 t[64][68];
  const int bid = blockIdx.x;
  const int tid = threadIdx.x;
  if (bid < 4096) {
    size_t i = ((size_t)bid * 256 + tid) * 8;
    float4 v0 = *(const float4*)(x + i);
    float4 v1 = *(const float4*)(x + i + 4);
    u32x4 r = { cvtpk(v0.x, v0.y), cvtpk(v0.z, v0.w), cvtpk(v1.x, v1.y), cvtpk(v1.z, v1.w) };
    *(u32x4*)(xbf + i) = r;
    return;
  }
  const float* src;
  u16* dst;
  int N, n0, k0;
  if (bid < 5120)      { int tt = bid - 4096; src = wq; dst = wqkvt;                        N = 2048; n0 = (tt & 31) << 6; k0 = (tt >> 5) << 6; }
  else if (bid < 5376) { int tt = bid - 5120; src = wk; dst = wqkvt + (size_t)2048 * 2048;  N = 512;  n0 = (tt & 7) << 6;  k0 = (tt >> 3) << 6; }
  else if (bid < 5632) { int tt = bid - 5376; src = wv; dst = wqkvt + (size_t)2560 * 2048;  N = 512;  n0 = (tt & 7) << 6;  k0 = (tt >> 3) << 6; }
  else                 { int tt = bid - 5632; src = wo; dst = wot;                          N = 2048; n0 = (tt & 31) << 6; k0 = (tt >> 5) << 6; }
#pragma unroll
  for (int r = 0; r < 4; ++r) {
    int k = r * 16 + (tid >> 4);
    int n = (tid & 15) * 4;
    float4 v = *(const float4*)(src + (size_t)(k0 + k) * N + n0 + n);
    t[n + 0][k] = f2bf(v.x);
    t[n + 1][k] = f2bf(v.y);
    t[n + 2][k] = f2bf(v.z);
    t[n + 3][k] = f2bf(v.w);
  }
  __syncthreads();
#pragma unroll
  for (int r = 0; r < 4; ++r) {
    int n = r * 16 + (tid >> 4);
    int k = (tid & 15) * 4;
    u16x4 o = { t[n][k], t[n][k + 1], t[n][k + 2], t[n][k + 3] };
    *(u16x4*)(dst + (size_t)(n0 + n) * 2048 + k0 + k) = o;
  }
}

// ------ bf16 GEMM v5: 2-phase skeleton with 3-chunk-ahead staging ------
template <int BM, int BN, typename OutT>
__global__ __launch_bounds__(512, 2)
void k_gemm8(const u16* __restrict__ A, const u16* __restrict__ Bt,
             OutT* __restrict__ C, int M, int N, int K, int nbx) {
  static_assert(BM == 128, "A staging assumes one full 512x16B round");
  constexpr int WM = 2, WN = 4;
  constexpr int MF = BM / 16 / WM;   // 4
  constexpr int NF = BN / 16 / WN;   // 2 (BN=128), 3 (BN=192), 4 (BN=256)
  __shared__ u16 sA[2][2][BM][32];
  __shared__ u16 sB[2][2][BN][32];
  const int nwg = gridDim.x;
  const int chunk = nwg >> 3;
  const int wg = (blockIdx.x & 7) * chunk + (blockIdx.x >> 3);
  const int m0 = (wg / nbx) * BM, n0 = (wg % nbx) * BN;
  const int tid = threadIdx.x;
  const int l = tid & 63;
  const int lo = l & 15, hi = l >> 4;
  const int wid = tid >> 6;
  const int wm = wid >> 2, wn = wid & 3;
  const int nkt = K >> 6;  // 64-wide K tiles

  f32x4 acc[MF][NF] = {};

  auto STAGE = [&](int ks, int t) {
    const int buf = t & 1;
    {
      const int D = tid * 16;
      const int row = D >> 6;
      const int srcb = (D & 63) ^ (((row >> 1) & 3) << 4);
      gload_lds16((const char*)(A + (size_t)(m0 + row) * K + t * 64 + ks * 32) + srcb,
                  (char*)(&sA[buf][ks][0][0]) + D);
    }
#pragma unroll
    for (int i = 0; i < 2; ++i) {
      const int u = i * 512 + tid;
      if (u < BN * 4) {
        const int D = u * 16;
        const int row = D >> 6;
        const int srcb = (D & 63) ^ (((row >> 1) & 3) << 4);
        gload_lds16((const char*)(Bt + (size_t)(n0 + row) * K + t * 64 + ks * 32) + srcb,
                    (char*)(&sB[buf][ks][0][0]) + D);
      }
    }
  };

  auto WAITVM = [&]() {  // leave exactly TWO phases' own issues in flight
    if constexpr (BN == 192) {
      if (wid < 4) asm volatile("s_waitcnt vmcnt(6)" ::: "memory");
      else         asm volatile("s_waitcnt vmcnt(4)" ::: "memory");
    } else if constexpr (BN == 256) {
      asm volatile("s_waitcnt vmcnt(6)" ::: "memory");
    } else {  // BN == 128
      asm volatile("s_waitcnt vmcnt(4)" ::: "memory");
    }
  };

  auto PHASE = [&](int buf, int ks, bool st, int st_ks, int st_t) {
    s16x8 a[MF], b[NF];
#pragma unroll
    for (int mf = 0; mf < MF; ++mf) {
      const int row = wm * (MF * 16) + mf * 16 + lo;
      a[mf] = *(const s16x8*)((const char*)(&sA[buf][ks][0][0]) + row * 64 +
                              ((hi * 16) ^ (((row >> 1) & 3) << 4)));
    }
#pragma unroll
    for (int nf = 0; nf < NF; ++nf) {
      const int row = wn * (NF * 16) + nf * 16 + lo;
      b[nf] = *(const s16x8*)((const char*)(&sB[buf][ks][0][0]) + row * 64 +
                              ((hi * 16) ^ (((row >> 1) & 3) << 4)));
    }
    if (st) STAGE(st_ks, st_t);
    __builtin_amdgcn_sched_barrier(0);
    __builtin_amdgcn_s_barrier();
    asm volatile("s_waitcnt lgkmcnt(0)" ::: "memory");
    __builtin_amdgcn_sched_barrier(0);
    __builtin_amdgcn_s_setprio(1);
#pragma unroll
    for (int mf = 0; mf < MF; ++mf)
#pragma unroll
      for (int nf = 0; nf < NF; ++nf)
        acc[mf][nf] = __builtin_amdgcn_mfma_f32_16x16x32_bf16(a[mf], b[nf], acc[mf][nf], 0, 0, 0);
    __builtin_amdgcn_s_setprio(0);
    if (st) WAITVM();
    else    asm volatile("s_waitcnt vmcnt(0)" ::: "memory");
    __builtin_amdgcn_sched_barrier(0);
    __builtin_amdgcn_s_barrier();
  };

  STAGE(0, 0);
  STAGE(1, 0);
  STAGE(0, 1);
  WAITVM();
  __builtin_amdgcn_s_barrier();

  for (int t = 0; t < nkt; ++t) {
    const int buf = t & 1;
    PHASE(buf, 0, t + 1 < nkt, 1, t + 1);
    PHASE(buf, 1, t + 2 < nkt, 0, t + 2);
  }

#pragma unroll
  for (int mf = 0; mf < MF; ++mf)
#pragma unroll
    for (int nf = 0; nf < NF; ++nf)
#pragma unroll
      for (int r = 0; r < 4; ++r) {
        const int row = m0 + wm * (MF * 16) + mf * 16 + hi * 4 + r;
        const int col = n0 + wn * (NF * 16) + nf * 16 + lo;
        if constexpr (__is_same(OutT, float)) C[(size_t)row * N + col] = acc[mf][nf][r];
        else                                  C[(size_t)row * N + col] = f2bf(acc[mf][nf][r]);
      }
}

// ---- k_post: fused {RMSNorm+RoPE (8 elems/lane)} + {V transpose} ----
__global__ __launch_bounds__(256) void k_post(const u16* __restrict__ qkv, u16* __restrict__ qn,
                                              u16* __restrict__ kn, u16* __restrict__ vt,
                                              const float* __restrict__ qs,
                                              const float* __restrict__ ksc,
                                              const float* __restrict__ cosb,
                                              const float* __restrict__ sinb) {
  __shared__ u16 t[64][68];
  const int bid = blockIdx.x;
  const int tid = threadIdx.x;
  if (bid < 5120) {
    // --- RMSNorm + RoPE ---
    const int i = tid & 63;
    const int sub = i & 7;
    const int j = (bid * 4 + (tid >> 6)) * 8 + (i >> 3);  // vector id
    const bool isQ = j < MROWS * 32;
    int m, head, incol;
    if (isQ) { m = j >> 5; head = j & 31; incol = head * 64; }
    else     { int j2 = j - MROWS * 32; m = j2 >> 3; head = j2 & 7; incol = 2048 + head * 64; }
    const u16x8 raw = *(const u16x8*)(qkv + (size_t)m * NQKV + incol + sub * 8);
    float f[8];
#pragma unroll
    for (int e = 0; e < 8; ++e) f[e] = bf2f(raw[e]);
    float ss = 0.f;
#pragma unroll
    for (int e = 0; e < 8; ++e) ss += f[e] * f[e];
    ss += __shfl_xor(ss, 1, 64);
    ss += __shfl_xor(ss, 2, 64);
    ss += __shfl_xor(ss, 4, 64);
    const float inv = rsqrtf(ss * (1.0f / 64.0f) + 1e-6f);
    const float* sc = isQ ? qs : ksc;
    float4 s0 = *(const float4*)(sc + sub * 8);
    float4 s1 = *(const float4*)(sc + sub * 8 + 4);
    float nx[8];
    nx[0] = f[0] * inv * s0.x; nx[1] = f[1] * inv * s0.y;
    nx[2] = f[2] * inv * s0.z; nx[3] = f[3] * inv * s0.w;
    nx[4] = f[4] * inv * s1.x; nx[5] = f[5] * inv * s1.y;
    nx[6] = f[6] * inv * s1.z; nx[7] = f[7] * inv * s1.w;
    const float sgn = (sub < 4) ? -1.f : 1.f;
    float rot[8];
#pragma unroll
    for (int e = 0; e < 8; ++e) rot[e] = sgn * __shfl_xor(nx[e], 4, 64);
    const int s = m & 2047;
    float4 c0 = *(const float4*)(cosb + s * 64 + sub * 8);
    float4 c1 = *(const float4*)(cosb + s * 64 + sub * 8 + 4);
    float4 n0 = *(const float4*)(sinb + s * 64 + sub * 8);
    float4 n1 = *(const float4*)(sinb + s * 64 + sub * 8 + 4);
    float outv[8];
    outv[0] = nx[0] * c0.x + rot[0] * n0.x; outv[1] = nx[1] * c0.y + rot[1] * n0.y;
    outv[2] = nx[2] * c0.z + rot[2] * n0.z; outv[3] = nx[3] * c0.w + rot[3] * n0.w;
    outv[4] = nx[4] * c1.x + rot[4] * n1.x; outv[5] = nx[5] * c1.y + rot[5] * n1.y;
    outv[6] = nx[6] * c1.z + rot[6] * n1.z; outv[7] = nx[7] * c1.w + rot[7] * n1.w;
    if (isQ) {
      const float qsc = 0.125f * 1.44269504088896f;  // fold 1/sqrt(HD), log2(e)
#pragma unroll
      for (int e = 0; e < 8; ++e) outv[e] *= qsc;
      u32x4 r = { cvtpk(outv[0], outv[1]), cvtpk(outv[2], outv[3]),
                  cvtpk(outv[4], outv[5]), cvtpk(outv[6], outv[7]) };
      *(u32x4*)(qn + (size_t)m * 2048 + incol + sub * 8) = r;
    } else {
      u32x4 r = { cvtpk(outv[0], outv[1]), cvtpk(outv[2], outv[3]),
                  cvtpk(outv[4], outv[5]), cvtpk(outv[6], outv[7]) };
      *(u32x4*)(kn + (size_t)m * 512 + head * 64 + sub * 8) = r;
    }
    return;
  }
  // --- V transpose: tile (s0, bk) ---
  const int tt = bid - 5120;
  const int s0 = (tt & 31) * 64;
  const int bk = tt >> 5;  // b*8 + kv
#pragma unroll
  for (int r = 0; r < 4; ++r) {
    int s = r * 16 + (tid >> 4);
    int d = (tid & 15) * 4;
    u16x4 v = *(const u16x4*)(qkv + (size_t)((bk >> 3) * 2048 + s0 + s) * NQKV + 2560 + (bk & 7) * 64 + d);
    t[d + 0][s] = v[0];
    t[d + 1][s] = v[1];
    t[d + 2][s] = v[2];
    t[d + 3][s] = v[3];
  }
  __syncthreads();
#pragma unroll
  for (int r = 0; r < 4; ++r) {
    int d = r * 16 + (tid >> 4);
    int sl = (tid & 15) * 4;
    u16x4 o = { t[d][sl], t[d][sl + 1], t[d][sl + 2], t[d][sl + 3] };
    *(u16x4*)(vt + (size_t)(bk * 64 + d) * 2048 + s0 + sl) = o;
  }
}

// ------- causal flash attention v8b (proven) -------
__global__ __launch_bounds__(512, 2) void k_attn(const u16* __restrict__ qn, const u16* __restrict__ kn,
                                                 const u16* __restrict__ vt, u16* __restrict__ aout) {
  __shared__ char sKV[4][2][64 * 128];  // [buf][K|V][row][128B], 64KB
  float* mO = (float*)&sKV[0][0][0];    // merge buffer alias: 128 x 65 f32
  float* mL = mO + 128 * 65;            // + 128 f32 lst
  const int bid = blockIdx.x;           // 512 blocks
  const int kvh = bid & 7;              // XCD-locality
  const int b = (bid >> 3) & 1;
  const int hsub = (bid >> 4) & 3;
  const int p = bid >> 6;               // 0..7
  const int h = kvh * 4 + hsub;
  const int tid = threadIdx.x, l = tid & 63;
  const int w = tid >> 6, qw = w & 3, half = w >> 2;
  const int l31 = l & 31, l5 = l >> 5;
  const int qtA = 15 - p, qtB = p;
  const u16* kbase = kn + (size_t)(b * 2048) * 512 + kvh * 64;
  const u16* vbase = vt + (size_t)((b * 8 + kvh) * 64) * 2048;
  const int st = tid >> 8;
  const int stid = tid & 255;
  const int srow = stid >> 3;
  const int scol = (stid & 7) * 8;
  const int sg_t = srow >> 4, sg_h = (srow >> 3) & 1, sg_j = srow & 7;
  const int krow0 = 32 * (sg_t >> 1) + 8 * ((sg_t & 1) * 2 + (sg_j >> 2)) + 4 * sg_h + (sg_j & 3);

  u16x8 krg0, krg1, vrg0, vrg1;
  int stbuf = 0;
  auto issue = [&](int baset) {
    const int tile = baset + st;
    const int kv0 = tile * 64;
    stbuf = tile & 3;
    krg0 = *(const u16x8*)(kbase + (size_t)(kv0 + srow) * 512 + scol);
    krg1 = *(const u16x8*)(kbase + (size_t)(kv0 + srow + 32) * 512 + scol);
    vrg0 = *(const u16x8*)(vbase + (size_t)srow * 2048 + kv0 + scol);
    vrg1 = *(const u16x8*)(vbase + (size_t)(srow + 32) * 2048 + kv0 + scol);
  };
  auto stash = [&]() {
    char* sK = sKV[stbuf][0];
    char* sV = sKV[stbuf][1];
    const int cb = scol * 2;
    const int k0_ = krow0, k1_ = krow0 + 32;
    *(u16x8*)(sK + k0_ * 128 + (cb ^ ((k0_ & 7) << 4))) = krg0;
    *(u16x8*)(sK + k1_ * 128 + (cb ^ ((k1_ & 7) << 4))) = krg1;
    const int r0 = srow, r1 = srow + 32;
    *(u16x8*)(sV + r0 * 128 + (cb ^ ((r0 & 7) << 4))) = vrg0;
    *(u16x8*)(sV + r1 * 128 + (cb ^ ((r1 & 7) << 4))) = vrg1;
  };

  s16x8 qf[4];
  f32x16 O0, O1;
  float lst;

  for (int mem = 0; mem < 2; ++mem) {
    const int qt = mem ? qtB : qtA;
    const int row = qw * 32 + l31;  // block-local q row
    {
      const u16* qp = qn + (size_t)(b * 2048 + qt * 128 + row) * 2048 + h * 64 + l5 * 8;
#pragma unroll
      for (int ki = 0; ki < 4; ++ki) qf[ki] = *(const s16x8*)(qp + ki * 16);
#pragma unroll
      for (int r = 0; r < 16; ++r) { O0[r] = 0.f; O1[r] = 0.f; }
      lst = 0.f;
    }
    issue(0);
    stash();
    __syncthreads();
    const int nss = qt + 1;
    for (int i = 0; i < nss; ++i) {
      const int T = 2 * i + half;  // my KV tile
      const char* sK = sKV[T & 3][0];
      const char* sV = sKV[T & 3][1];
      if (i + 1 < nss) issue(2 * i + 2);
      // ---- QK^T (keys sigma-permuted)
      f32x16 sc0, sc1;
#pragma unroll
      for (int r = 0; r < 16; ++r) { sc0[r] = 0.f; sc1[r] = 0.f; }
      __builtin_amdgcn_s_setprio(1);
#pragma unroll
      for (int ki = 0; ki < 4; ++ki) {
        const int cb = ki * 32 + l5 * 16;
        const int r0 = l31, r1 = 32 + l31;
        s16x8 a0 = *(const s16x8*)(sK + r0 * 128 + (cb ^ ((r0 & 7) << 4)));
        s16x8 a1 = *(const s16x8*)(sK + r1 * 128 + (cb ^ ((r1 & 7) << 4)));
        sc0 = __builtin_amdgcn_mfma_f32_32x32x16_bf16(a0, qf[ki], sc0, 0, 0, 0);
        sc1 = __builtin_amdgcn_mfma_f32_32x32x16_bf16(a1, qf[ki], sc1, 0, 0, 0);
      }
      __builtin_amdgcn_s_setprio(0);
      // ---- causal mask (sigma-inverse key index); last superstep only
      if (T >= 2 * qt) {
        const int qrow = qt * 128 + row;
        const int kb0 = T * 64 + 8 * l5;
#pragma unroll
        for (int r = 0; r < 16; ++r) {
          const int klocal = 16 * (r >> 3) + 4 * ((r >> 2) & 1) + (r & 3);
          if (kb0 + klocal > qrow) sc0[r] = -1e30f;
          if (kb0 + 32 + klocal > qrow) sc1[r] = -1e30f;
        }
      }
      // ---- fixed-scale softmax: P = exp2(score)
      float rs = 0.f;
      u32 pk0[4][2], pk1[4][2];
#pragma unroll
      for (int g = 0; g < 4; ++g) {
        float a0 = EXP2(sc0[4*g+0]), a1 = EXP2(sc0[4*g+1]);
        float a2 = EXP2(sc0[4*g+2]), a3 = EXP2(sc0[4*g+3]);
        float b0 = EXP2(sc1[4*g+0]), b1 = EXP2(sc1[4*g+1]);
        float b2 = EXP2(sc1[4*g+2]), b3 = EXP2(sc1[4*g+3]);
        rs += ((a0 + a1) + (a2 + a3)) + ((b0 + b1) + (b2 + b3));
        pk0[g][0] = cvtpk(a0, a1);
        pk0[g][1] = cvtpk(a2, a3);
        pk1[g][0] = cvtpk(b0, b1);
        pk1[g][1] = cvtpk(b2, b3);
      }
      rs += __shfl_xor(rs, 32, 64);
      lst += rs;
      // ---- PV: P already in B-frag layout; zero shuffles
#define PV_STEP(PK, GB, KB)                                                   \
      {                                                                       \
        u32x4 wv_ = { PK[GB][0], PK[GB][1], PK[GB+1][0], PK[GB+1][1] };       \
        s16x8 pb = __builtin_bit_cast(s16x8, wv_);                            \
        const int cb = (KB) * 32 + l5 * 16;                                   \
        const int rv0 = l31, rv1 = 32 + l31;                                  \
        s16x8 v0 = *(const s16x8*)(sV + rv0 * 128 + (cb ^ ((rv0 & 7) << 4))); \
        s16x8 v1 = *(const s16x8*)(sV + rv1 * 128 + (cb ^ ((rv1 & 7) << 4))); \
        __builtin_amdgcn_s_setprio(1);                                        \
        O0 = __builtin_amdgcn_mfma_f32_32x32x16_bf16(v0, pb, O0, 0, 0, 0);    \
        O1 = __builtin_amdgcn_mfma_f32_32x32x16_bf16(v1, pb, O1, 0, 0, 0);    \
        __builtin_amdgcn_s_setprio(0);                                        \
      }
      PV_STEP(pk0, 0, 0)
      PV_STEP(pk0, 2, 1)
      PV_STEP(pk1, 0, 2)
      PV_STEP(pk1, 2, 3)
#undef PV_STEP
      if (i + 1 < nss) stash();
      __syncthreads();
    }
    // ---- merge the two halves' partial (O, lst), then store
    if (half == 1) {
#pragma unroll
      for (int g = 0; g < 4; ++g)
#pragma unroll
        for (int j = 0; j < 4; ++j) {
          const int d = 8 * g + 4 * l5 + j;
          mO[row * 65 + d] = O0[4*g+j];
          mO[row * 65 + 32 + d] = O1[4*g+j];
        }
      if (l5 == 0) mL[row] = lst;
    }
    __syncthreads();
    if (half == 0) {
      const float inv = 1.0f / (lst + mL[row]);
      const size_t rowoff = (size_t)(b * 2048 + qt * 128 + row) * 2048 + h * 64;
#pragma unroll
      for (int g = 0; g < 4; ++g) {
        const int d0 = 8 * g + 4 * l5;
        u16x4 o0 = { f2bf((O0[4*g+0] + mO[row*65+d0+0]) * inv),
                     f2bf((O0[4*g+1] + mO[row*65+d0+1]) * inv),
                     f2bf((O0[4*g+2] + mO[row*65+d0+2]) * inv),
                     f2bf((O0[4*g+3] + mO[row*65+d0+3]) * inv) };
        *(u16x4*)(aout + rowoff + d0) = o0;
        u16x4 o1 = { f2bf((O1[4*g+0] + mO[row*65+32+d0+0]) * inv),
                     f2bf((O1[4*g+1] + mO[row*65+32+d0+1]) * inv),
                     f2bf((O1[4*g+2] + mO[row*65+32+d0+2]) * inv),
                     f2bf((O1[4*g+3] + mO[row*65+32+d0+3]) * inv) };
        *(u16x4*)(aout + rowoff + 32 + d0) = o1;
      }
    }
    __syncthreads();  // merge reads done before next member's staging
  }
}

extern "C" void kernel_launch(void* const* d_in, const int* in_sizes, int n_in,
                              void* d_out, int out_size, void* d_ws, size_t ws_size,
                              hipStream_t stream) {
  (void)in_sizes; (void)n_in; (void)out_size; (void)ws_size;
  const float* x    = (const float*)d_in[0];
  const float* wq   = (const float*)d_in[1];
  const float* wk   = (const float*)d_in[2];
  const float* wv   = (const float*)d_in[3];
  const float* wo   = (const float*)d_in[4];
  const float* qs   = (const float*)d_in[5];
  const float* ksc  = (const float*)d_in[6];
  const float* cosb = (const float*)d_in[7];
  const float* sinb = (const float*)d_in[8];
  float* out = (float*)d_out;
  char* ws = (char*)d_ws;
  u16* xbf   = (u16*)(ws);                 // 16 MB  4096x2048 bf16
  u16* wqkvt = (u16*)(ws + 16777216);      // 12 MB  3072x2048 bf16 (W^T)
  u16* wot   = (u16*)(ws + 29360128);      // 8 MB   2048x2048 bf16 (Wo^T)
  u16* qkv   = (u16*)(ws + 37748736);      // 24 MB  4096x3072 bf16
  u16* qn    = (u16*)(ws + 62914560);      // 16 MB  4096x2048 bf16
  u16* kn    = (u16*)(ws + 79691776);      // 4 MB   4096x512 bf16
  u16* vt    = (u16*)(ws + 83886080);      // 4 MB   (b,kv,d) x 2048 bf16
  u16* aout  = (u16*)(ws + 88080384);      // 16 MB  4096x2048 bf16

  // fused prep: x convert (4096 blocks) + 4 weight transposes (2560 blocks)
  k_prep<<<6656, 256, 0, stream>>>(x, wq, wk, wv, wo, xbf, wqkvt, wot);
  // QKV: 128x192 tiles -> 32x16 = 512 blocks, 2 blocks/CU (80KB LDS), exact fill
  k_gemm8<128, 192, u16><<<512, 512, 0, stream>>>(xbf, wqkvt, qkv, MROWS, NQKV, 2048, 16);
  // fused post: RMSNorm+RoPE (5120 blocks) + V transpose (512 blocks)
  k_post<<<5632, 256, 0, stream>>>(qkv, qn, kn, vt, qs, ksc, cosb, sinb);
  k_attn<<<512, 512, 0, stream>>>(qn, kn, vt, aout);
  // OUT: 128x128 tiles -> 32x16 = 512 blocks, 2 blocks/CU (64KB LDS), exact fill
  k_gemm8<128, 128, float><<<512, 512, 0, stream>>>(aout, wot, out, MROWS, DMODEL, 2048, 16);
}